// Round 5
// baseline (863.586 us; speedup 1.0000x reference)
//
#include <hip/hip_runtime.h>
#include <hip/hip_bf16.h>
#include <math.h>

#define DIMC 768
#define HEADS 12
#define HD 64
#define EXPERTS 8
#define HID 3072
#define BB 8
#define NN 196
#define TT (BB*NN)      // 1568
#define CAP_ROWS 3648   // 2*TT + 8*64 headroom, multiple of 64
#define LN_EPS 1e-5f

typedef float f32x4_t __attribute__((ext_vector_type(4)));
typedef short bf16x8_t __attribute__((ext_vector_type(8)));

__device__ __forceinline__ unsigned short f2bf(float f) {
    unsigned int u = __float_as_uint(f);
    u += 0x7FFFu + ((u >> 16) & 1u);   // round-to-nearest-even
    return (unsigned short)(u >> 16);
}

// ---------------- LayerNorm: one block per token, 256 threads, D=768 ----------------
__global__ void ln_kernel(const float* __restrict__ x, const float* __restrict__ g,
                          const float* __restrict__ b, float* __restrict__ out_f,
                          unsigned short* __restrict__ out_bf) {
    int t = blockIdx.x;
    const float* xr = x + (size_t)t * DIMC;
    int tid = threadIdx.x;
    float v0 = xr[tid], v1 = xr[tid + 256], v2 = xr[tid + 512];
    __shared__ float red[256];
    red[tid] = v0 + v1 + v2;
    __syncthreads();
    for (int off = 128; off > 0; off >>= 1) {
        if (tid < off) red[tid] += red[tid + off];
        __syncthreads();
    }
    float mu = red[0] * (1.0f / DIMC);
    __syncthreads();
    float d0 = v0 - mu, d1 = v1 - mu, d2 = v2 - mu;
    red[tid] = d0*d0 + d1*d1 + d2*d2;
    __syncthreads();
    for (int off = 128; off > 0; off >>= 1) {
        if (tid < off) red[tid] += red[tid + off];
        __syncthreads();
    }
    float rstd = rsqrtf(red[0] * (1.0f / DIMC) + LN_EPS);
    float o0 = d0 * rstd * g[tid]       + b[tid];
    float o1 = d1 * rstd * g[tid + 256] + b[tid + 256];
    float o2 = d2 * rstd * g[tid + 512] + b[tid + 512];
    if (out_f) {
        float* o = out_f + (size_t)t * DIMC;
        o[tid] = o0; o[tid + 256] = o1; o[tid + 512] = o2;
    }
    if (out_bf) {
        unsigned short* o = out_bf + (size_t)t * DIMC;
        o[tid] = f2bf(o0); o[tid + 256] = f2bf(o1); o[tid + 512] = f2bf(o2);
    }
}

// ---------------- fp32 tiled GEMM (round-3 known-good): C = A @ B + bias (+res) ----------------
// grid (M/32, N/64), block 256. M%32==0, N%64==0, K%32==0.
__global__ void gemm_f32(const float* __restrict__ A, const float* __restrict__ B,
                         const float* __restrict__ bias, const float* __restrict__ res,
                         float* __restrict__ C, int M, int N, int K) {
    __shared__ float As[32][33];
    __shared__ float Bs[32][65];
    int m0 = blockIdx.x * 32;
    int n0 = blockIdx.y * 64;
    int tid = threadIdx.x;
    int ty = tid / 16, tx = tid % 16;
    float acc[2][4] = {};
    for (int k0 = 0; k0 < K; k0 += 32) {
        {
            int c = tid % 32, rr = tid / 32;
            #pragma unroll
            for (int p = 0; p < 4; ++p) {
                int r = rr + p * 8;
                As[r][c] = A[(size_t)(m0 + r) * K + k0 + c];
            }
        }
        {
            int c = tid % 64, rr = tid / 64;
            #pragma unroll
            for (int p = 0; p < 8; ++p) {
                int r = rr + p * 4;
                Bs[r][c] = B[(size_t)(k0 + r) * N + n0 + c];
            }
        }
        __syncthreads();
        #pragma unroll
        for (int k = 0; k < 32; ++k) {
            float a0 = As[ty*2+0][k];
            float a1 = As[ty*2+1][k];
            #pragma unroll
            for (int j = 0; j < 4; ++j) {
                float bj = Bs[k][tx*4+j];
                acc[0][j] += a0 * bj;
                acc[1][j] += a1 * bj;
            }
        }
        __syncthreads();
    }
    #pragma unroll
    for (int i = 0; i < 2; ++i) {
        int r = m0 + ty*2 + i;
        #pragma unroll
        for (int j = 0; j < 4; ++j) {
            int c = n0 + tx*4 + j;
            float v = acc[i][j] + bias[c];
            if (res) v += res[(size_t)r * N + c];
            C[(size_t)r * N + c] = v;
        }
    }
}

// ---------------- attention: grid (B*H, 7), block 256, fp32, LDS-tiled ----------------
__global__ void attn_kernel(const float* __restrict__ qkv, float* __restrict__ o) {
    int bh = blockIdx.x;
    int b = bh / HEADS, h = bh % HEADS;
    int i0 = blockIdx.y * 32;
    const float* base = qkv + (size_t)b * NN * 2304 + h * 64;
    __shared__ float qts[64][36];    // [d][i] transposed Q
    __shared__ float kv[64][68];     // K-tile or V-tile, row-major
    __shared__ float ps[32][201];    // scores [i][j]
    int tid = threadIdx.x;

    // stage Q transposed: 32 rows x 64 d = 512 float4, 2/thread
    #pragma unroll
    for (int p = 0; p < 2; ++p) {
        int f = p * 256 + tid;
        int i = f >> 4, d0 = (f & 15) * 4;
        int n = i0 + i;
        float4 v = make_float4(0.f, 0.f, 0.f, 0.f);
        if (n < NN) v = *(const float4*)(base + (size_t)n * 2304 + d0);
        qts[d0 + 0][i] = v.x; qts[d0 + 1][i] = v.y; qts[d0 + 2][i] = v.z; qts[d0 + 3][i] = v.w;
    }

    int txq = tid & 7, tyq = tid >> 3;    // QK: i4 = 4*txq, j rows {2tyq, 2tyq+1}
    int txp = tid & 15, typ = tid >> 4;   // PV: d4 = 4*txp, i rows {2typ, 2typ+1}

    // ---- S^T = K @ Q^T, tiles of 64 j ----
    for (int jt = 0; jt < 4; ++jt) {
        int j0 = jt * 64;
        __syncthreads();   // protect kv (and cover qts writes on first iter)
        #pragma unroll
        for (int p = 0; p < 4; ++p) {
            int f = p * 256 + tid;
            int jj = f >> 4, d0 = (f & 15) * 4;
            int j = j0 + jj;
            float4 v = make_float4(0.f, 0.f, 0.f, 0.f);
            if (j < NN) v = *(const float4*)(base + (size_t)j * 2304 + 768 + d0);
            *(float4*)&kv[jj][d0] = v;
        }
        __syncthreads();
        float s[2][4] = {};
        #pragma unroll
        for (int d = 0; d < 64; ++d) {
            float k0v = kv[2 * tyq][d], k1v = kv[2 * tyq + 1][d];
            float4 q4 = *(const float4*)&qts[d][4 * txq];
            s[0][0] += k0v * q4.x; s[0][1] += k0v * q4.y;
            s[0][2] += k0v * q4.z; s[0][3] += k0v * q4.w;
            s[1][0] += k1v * q4.x; s[1][1] += k1v * q4.y;
            s[1][2] += k1v * q4.z; s[1][3] += k1v * q4.w;
        }
        #pragma unroll
        for (int v2 = 0; v2 < 2; ++v2) {
            int j = j0 + 2 * tyq + v2;
            if (j < NN) {
                ps[4 * txq + 0][j] = s[v2][0] * 0.125f;
                ps[4 * txq + 1][j] = s[v2][1] * 0.125f;
                ps[4 * txq + 2][j] = s[v2][2] * 0.125f;
                ps[4 * txq + 3][j] = s[v2][3] * 0.125f;
            }
        }
    }
    __syncthreads();

    // ---- softmax: 32 rows x 8 lanes ----
    {
        int i = tid >> 3, l = tid & 7;
        float mx = -1e30f;
        for (int j = l; j < NN; j += 8) mx = fmaxf(mx, ps[i][j]);
        #pragma unroll
        for (int off = 4; off > 0; off >>= 1) mx = fmaxf(mx, __shfl_xor(mx, off, 8));
        float sum = 0.f;
        for (int j = l; j < NN; j += 8) { float e = expf(ps[i][j] - mx); ps[i][j] = e; sum += e; }
        #pragma unroll
        for (int off = 4; off > 0; off >>= 1) sum += __shfl_xor(sum, off, 8);
        float inv = 1.f / sum;
        for (int j = l; j < NN; j += 8) ps[i][j] *= inv;
    }

    // ---- O = P @ V, tiles of 64 j ----
    float acc[2][4] = {};
    for (int jt = 0; jt < 4; ++jt) {
        int j0 = jt * 64;
        __syncthreads();
        #pragma unroll
        for (int p = 0; p < 4; ++p) {
            int f = p * 256 + tid;
            int jj = f >> 4, d0 = (f & 15) * 4;
            int j = j0 + jj;
            float4 v = make_float4(0.f, 0.f, 0.f, 0.f);
            if (j < NN) v = *(const float4*)(base + (size_t)j * 2304 + 1536 + d0);
            *(float4*)&kv[jj][d0] = v;
        }
        __syncthreads();
        if (jt < 3) {
            #pragma unroll
            for (int jj = 0; jj < 64; ++jj) {
                int j = j0 + jj;
                float p0 = ps[2 * typ][j], p1 = ps[2 * typ + 1][j];
                float4 v4 = *(const float4*)&kv[jj][4 * txp];
                acc[0][0] += p0 * v4.x; acc[0][1] += p0 * v4.y;
                acc[0][2] += p0 * v4.z; acc[0][3] += p0 * v4.w;
                acc[1][0] += p1 * v4.x; acc[1][1] += p1 * v4.y;
                acc[1][2] += p1 * v4.z; acc[1][3] += p1 * v4.w;
            }
        } else {
            for (int jj = 0; jj < NN - 192; ++jj) {
                int j = j0 + jj;
                float p0 = ps[2 * typ][j], p1 = ps[2 * typ + 1][j];
                float4 v4 = *(const float4*)&kv[jj][4 * txp];
                acc[0][0] += p0 * v4.x; acc[0][1] += p0 * v4.y;
                acc[0][2] += p0 * v4.z; acc[0][3] += p0 * v4.w;
                acc[1][0] += p1 * v4.x; acc[1][1] += p1 * v4.y;
                acc[1][2] += p1 * v4.z; acc[1][3] += p1 * v4.w;
            }
        }
    }
    #pragma unroll
    for (int v2 = 0; v2 < 2; ++v2) {
        int n = i0 + 2 * typ + v2;
        if (n < NN) {
            float4 ov = make_float4(acc[v2][0], acc[v2][1], acc[v2][2], acc[v2][3]);
            *(float4*)(o + ((size_t)(b * NN + n)) * DIMC + h * 64 + 4 * txp) = ov;
        }
    }
}

// ---------------- gate: one wave per token (fp32 — expert choice must match ref) ----------------
__global__ void gate_kernel(const float* __restrict__ xn, const float* __restrict__ gw,
                            int* __restrict__ tok_e, float* __restrict__ tok_g,
                            int* __restrict__ counts) {
    int t = blockIdx.x;
    int lane = threadIdx.x;  // 64
    float acc[8] = {};
    const float* xr = xn + (size_t)t * DIMC;
    for (int i = lane; i < DIMC; i += 64) {
        float xi = xr[i];
        const float* gr = gw + (size_t)i * 8;
        #pragma unroll
        for (int e = 0; e < 8; ++e) acc[e] += xi * gr[e];
    }
    #pragma unroll
    for (int e = 0; e < 8; ++e) {
        #pragma unroll
        for (int off = 32; off > 0; off >>= 1) acc[e] += __shfl_down(acc[e], off, 64);
    }
    if (lane == 0) {
        int e0 = 0; float l0 = acc[0];
        #pragma unroll
        for (int e = 1; e < 8; ++e) if (acc[e] > l0) { l0 = acc[e]; e0 = e; }
        int e1 = -1; float l1 = -3e38f;
        #pragma unroll
        for (int e = 0; e < 8; ++e) if (e != e0 && acc[e] > l1) { l1 = acc[e]; e1 = e; }
        float pp = expf(l1 - l0);
        float g0 = 1.f / (1.f + pp);
        float g1 = pp / (1.f + pp);
        tok_e[t*2] = e0; tok_e[t*2+1] = e1;
        tok_g[t*2] = g0; tok_g[t*2+1] = g1;
        atomicAdd(&counts[e0], 1);
        atomicAdd(&counts[e1], 1);
    }
}

__global__ void init_kernel(int* __restrict__ counts, int* __restrict__ row2tok, int cap) {
    int i = blockIdx.x * blockDim.x + threadIdx.x;
    if (i < 8) counts[i] = 0;
    if (i < cap) row2tok[i] = -1;
}

__global__ void offsets_kernel(const int* __restrict__ counts, int* __restrict__ offsets,
                               int* __restrict__ cursor) {
    if (threadIdx.x == 0 && blockIdx.x == 0) {
        int off = 0;
        for (int e = 0; e < 8; ++e) {
            offsets[e] = off;
            cursor[e]  = off;
            off += ((counts[e] + 63) / 64) * 64;  // pad each segment to BM=64
        }
        offsets[8] = off;
    }
}

__global__ void fill_kernel(const int* __restrict__ tok_e, int* __restrict__ cursor,
                            int* __restrict__ row2tok, int* __restrict__ tok_row) {
    int t = blockIdx.x * blockDim.x + threadIdx.x;
    if (t >= TT) return;
    #pragma unroll
    for (int k = 0; k < 2; ++k) {
        int e = tok_e[t*2+k];
        int slot = atomicAdd(&cursor[e], 1);
        row2tok[slot] = t;
        tok_row[t*2+k] = slot;
    }
}

// ---------------- batched transpose + fp32->bf16: src [B][R][C] -> dst [B][C][R] ----------------
// grid (C/64, R/64, B), block 256
__global__ void transpose_bf16(const float* __restrict__ src, unsigned short* __restrict__ dst,
                               int R, int C) {
    __shared__ float tile[64][65];
    const float* s = src + (size_t)blockIdx.z * R * C;
    unsigned short* d = dst + (size_t)blockIdx.z * R * C;
    int c0 = blockIdx.x * 64, r0 = blockIdx.y * 64;
    int tid = threadIdx.x;
    int tr = tid >> 4;            // 0..15
    int tc = (tid & 15) * 4;      // 0..60
    #pragma unroll
    for (int p = 0; p < 4; ++p) {
        int r = tr + p * 16;
        const float4 v = *(const float4*)(s + (size_t)(r0 + r) * C + c0 + tc);
        tile[r][tc+0] = v.x; tile[r][tc+1] = v.y; tile[r][tc+2] = v.z; tile[r][tc+3] = v.w;
    }
    __syncthreads();
    #pragma unroll
    for (int p = 0; p < 4; ++p) {
        int c = tr + p * 16;      // local col -> dst row
        ushort4 o;
        o.x = f2bf(tile[tc+0][c]);
        o.y = f2bf(tile[tc+1][c]);
        o.z = f2bf(tile[tc+2][c]);
        o.w = f2bf(tile[tc+3][c]);
        *(ushort4*)(d + (size_t)(c0 + c) * R + r0 + tc) = o;
    }
}

// ---------------- grouped bf16 MFMA GEMM ----------------
// C[rows][N] = act( gather(A)[rows][K] @ Bt[e][N][K]^T + bias[e][N] )
// BM=BN=BK=64, 256 threads = 4 waves (2x2), each wave 32x32 via 2x2 16x16x32 MFMA.
// grid (CAP_ROWS/64, N/64). LDS tiles XOR-swizzled: byte ^= (row&7)<<4.
template<int GATHER, int GELU, int OUT_BF16>
__global__ void mfma_gemm_grouped(const unsigned short* __restrict__ A,
                                  const unsigned short* __restrict__ Bt,
                                  const float* __restrict__ bias,
                                  const int* __restrict__ offsets,
                                  const int* __restrict__ row2tok,
                                  void* __restrict__ Cout,
                                  int N, int K) {
    __shared__ unsigned short As[64 * 64];
    __shared__ unsigned short Bs[64 * 64];
    __shared__ int toks[64];

    int r0 = blockIdx.x * 64;
    if (r0 >= offsets[8]) return;
    int e = 0;
    while (r0 >= offsets[e + 1]) ++e;
    int n0 = blockIdx.y * 64;
    int tid = threadIdx.x;
    if (GATHER && tid < 64) toks[tid] = row2tok[r0 + tid];
    __syncthreads();

    const unsigned short* Be = Bt + (size_t)e * N * K;

    int sr = tid >> 3;        // 0..31 (staging row, +32 second pass)
    int sq = tid & 7;         // 0..7  (16B chunk within 128B row)
    int lane = tid & 63;
    int wid = tid >> 6;
    int wm = (wid >> 1) * 32;
    int wn = (wid & 1) * 32;
    int colb_base = (lane >> 4) * 16;
    int lrow = lane & 15;

    f32x4_t acc[2][2] = {};

    for (int k0 = 0; k0 < K; k0 += 64) {
        #pragma unroll
        for (int p = 0; p < 2; ++p) {
            int r = sr + p * 32;
            int swz = (sq * 16) ^ ((r & 7) << 4);
            int4 va = {0, 0, 0, 0};
            if (GATHER) {
                int tok = toks[r];
                if (tok >= 0) va = *(const int4*)(A + (size_t)tok * K + k0 + sq * 8);
            } else {
                va = *(const int4*)(A + (size_t)(r0 + r) * K + k0 + sq * 8);
            }
            *(int4*)((char*)As + r * 128 + swz) = va;
            int4 vb = *(const int4*)(Be + (size_t)(n0 + r) * K + k0 + sq * 8);
            *(int4*)((char*)Bs + r * 128 + swz) = vb;
        }
        __syncthreads();
        #pragma unroll
        for (int kk = 0; kk < 2; ++kk) {
            int colb = kk * 64 + colb_base;
            bf16x8_t a[2], b[2];
            #pragma unroll
            for (int i = 0; i < 2; ++i) {
                int ra = wm + i * 16 + lrow;
                a[i] = *(const bf16x8_t*)((const char*)As + ra * 128 + (colb ^ ((ra & 7) << 4)));
                int rb = wn + i * 16 + lrow;
                b[i] = *(const bf16x8_t*)((const char*)Bs + rb * 128 + (colb ^ ((rb & 7) << 4)));
            }
            #pragma unroll
            for (int mi = 0; mi < 2; ++mi)
                #pragma unroll
                for (int ni = 0; ni < 2; ++ni)
                    acc[mi][ni] = __builtin_amdgcn_mfma_f32_16x16x32_bf16(
                        a[mi], b[ni], acc[mi][ni], 0, 0, 0);
        }
        __syncthreads();
    }

    #pragma unroll
    for (int mi = 0; mi < 2; ++mi) {
        #pragma unroll
        for (int ni = 0; ni < 2; ++ni) {
            int col = n0 + wn + ni * 16 + lrow;
            float bv = GELU ? bias[(size_t)e * N + col] : 0.f;
            #pragma unroll
            for (int j = 0; j < 4; ++j) {
                int row = r0 + wm + mi * 16 + (lane >> 4) * 4 + j;
                float v = acc[mi][ni][j] + bv;
                if (GELU) v = 0.5f * v * (1.f + erff(v * 0.70710678f));
                if (OUT_BF16)
                    ((unsigned short*)Cout)[(size_t)row * N + col] = f2bf(v);
                else
                    ((float*)Cout)[(size_t)row * N + col] = v;
            }
        }
    }
}

// ---------------- combine: out = x_res + sum_k g_k*(y[row_k] + b2[e_k]) ----------------
__global__ void combine_kernel(const float* __restrict__ x_res, const float* __restrict__ y,
                               const float* __restrict__ b2, const int* __restrict__ tok_e,
                               const float* __restrict__ tok_g, const int* __restrict__ tok_row,
                               float* __restrict__ out) {
    int t = blockIdx.x;
    int c = blockIdx.y * 256 + threadIdx.x;
    int e0 = tok_e[t*2], e1 = tok_e[t*2+1];
    float g0 = tok_g[t*2], g1 = tok_g[t*2+1];
    int r0 = tok_row[t*2], r1 = tok_row[t*2+1];
    float v = x_res[(size_t)t * DIMC + c]
            + g0 * (y[(size_t)r0 * DIMC + c] + b2[(size_t)e0 * DIMC + c])
            + g1 * (y[(size_t)r1 * DIMC + c] + b2[(size_t)e1 * DIMC + c]);
    out[(size_t)t * DIMC + c] = v;
}

extern "C" void kernel_launch(void* const* d_in, const int* in_sizes, int n_in,
                              void* d_out, int out_size, void* d_ws, size_t ws_size,
                              hipStream_t stream) {
    const float* x      = (const float*)d_in[0];
    const float* ln1_g  = (const float*)d_in[1];
    const float* ln1_b  = (const float*)d_in[2];
    const float* qkv_w  = (const float*)d_in[3];
    const float* qkv_b  = (const float*)d_in[4];
    const float* proj_w = (const float*)d_in[5];
    const float* proj_b = (const float*)d_in[6];
    const float* ln2_g  = (const float*)d_in[7];
    const float* ln2_b  = (const float*)d_in[8];
    const float* gate_w = (const float*)d_in[9];
    const float* w1     = (const float*)d_in[10];
    const float* b1     = (const float*)d_in[11];
    const float* w2     = (const float*)d_in[12];
    const float* b2     = (const float*)d_in[13];
    float* out = (float*)d_out;

    char* p = (char*)d_ws;
    auto alloc = [&](size_t nbytes) {
        void* r = (void*)p;
        p += (nbytes + 255) & ~(size_t)255;
        return r;
    };
    float*          xn1     = (float*)alloc((size_t)TT * DIMC * 4);
    float*          qkv     = (float*)alloc((size_t)TT * 2304 * 4);
    float*          attn_o  = (float*)alloc((size_t)TT * DIMC * 4);
    float*          x_res   = (float*)alloc((size_t)TT * DIMC * 4);
    float*          xn2_f   = (float*)alloc((size_t)TT * DIMC * 4);
    unsigned short* xn2_bf  = (unsigned short*)alloc((size_t)TT * DIMC * 2);
    unsigned short* h       = (unsigned short*)alloc((size_t)CAP_ROWS * HID * 2);
    float*          y       = (float*)alloc((size_t)CAP_ROWS * DIMC * 4);
    unsigned short* w1t     = (unsigned short*)alloc((size_t)EXPERTS * DIMC * HID * 2);
    unsigned short* w2t     = (unsigned short*)alloc((size_t)EXPERTS * DIMC * HID * 2);
    float*          tok_g   = (float*)alloc((size_t)2 * TT * 4);
    int*            tok_e   = (int*)alloc((size_t)2 * TT * 4);
    int*            tok_row = (int*)alloc((size_t)2 * TT * 4);
    int*            row2tok = (int*)alloc((size_t)CAP_ROWS * 4);
    int*            counts  = (int*)alloc(32 * 4);
    int*            offsets = (int*)alloc(32 * 4);
    int*            cursor  = (int*)alloc(32 * 4);

    init_kernel<<<(CAP_ROWS + 255) / 256, 256, 0, stream>>>(counts, row2tok, CAP_ROWS);

    // weight transposes (independent of activations)
    transpose_bf16<<<dim3(HID / 64, DIMC / 64, EXPERTS), 256, 0, stream>>>(w1, w1t, DIMC, HID);
    transpose_bf16<<<dim3(DIMC / 64, HID / 64, EXPERTS), 256, 0, stream>>>(w2, w2t, HID, DIMC);

    ln_kernel<<<TT, 256, 0, stream>>>(x, ln1_g, ln1_b, xn1, nullptr);

    gemm_f32<<<dim3(TT / 32, 2304 / 64), 256, 0, stream>>>(xn1, qkv_w, qkv_b, nullptr, qkv,
                                                           TT, 2304, 768);

    attn_kernel<<<dim3(BB * HEADS, 7), 256, 0, stream>>>(qkv, attn_o);

    gemm_f32<<<dim3(TT / 32, 768 / 64), 256, 0, stream>>>(attn_o, proj_w, proj_b, x, x_res,
                                                          TT, 768, 768);

    ln_kernel<<<TT, 256, 0, stream>>>(x_res, ln2_g, ln2_b, xn2_f, xn2_bf);

    gate_kernel<<<TT, 64, 0, stream>>>(xn2_f, gate_w, tok_e, tok_g, counts);

    offsets_kernel<<<1, 64, 0, stream>>>(counts, offsets, cursor);

    fill_kernel<<<(TT + 255) / 256, 256, 0, stream>>>(tok_e, cursor, row2tok, tok_row);

    mfma_gemm_grouped<1, 1, 1><<<dim3(CAP_ROWS / 64, HID / 64), 256, 0, stream>>>(
        xn2_bf, w1t, b1, offsets, row2tok, h, HID, DIMC);

    mfma_gemm_grouped<0, 0, 0><<<dim3(CAP_ROWS / 64, DIMC / 64), 256, 0, stream>>>(
        h, w2t, nullptr, offsets, row2tok, y, DIMC, HID);

    combine_kernel<<<dim3(TT, 3), 256, 0, stream>>>(x_res, y, b2, tok_e, tok_g, tok_row, out);
}

// Round 6
// 533.588 us; speedup vs baseline: 1.6185x; 1.6185x over previous
//
#include <hip/hip_runtime.h>
#include <hip/hip_bf16.h>
#include <math.h>

#define DIMC 768
#define HEADS 12
#define HD 64
#define EXPERTS 8
#define HID 3072
#define BB 8
#define NN 196
#define TT (BB*NN)      // 1568
#define CAP_ROWS 3648   // 2*TT + 8*64 headroom, multiple of 64
#define LN_EPS 1e-5f

typedef float f32x4_t __attribute__((ext_vector_type(4)));
typedef short bf16x8_t __attribute__((ext_vector_type(8)));

__device__ __forceinline__ unsigned short f2bf(float f) {
    unsigned int u = __float_as_uint(f);
    u += 0x7FFFu + ((u >> 16) & 1u);   // round-to-nearest-even
    return (unsigned short)(u >> 16);
}
__device__ __forceinline__ float bf2f(unsigned short u) {
    return __uint_as_float(((unsigned int)u) << 16);
}

// ---------------- LayerNorm: one block per token, 256 threads, D=768 ----------------
// Emits optional fp32, and optional bf16 hi/lo split (hi alone = plain bf16 cast).
__global__ void ln_kernel(const float* __restrict__ x, const float* __restrict__ g,
                          const float* __restrict__ b, float* __restrict__ out_f,
                          unsigned short* __restrict__ out_hi,
                          unsigned short* __restrict__ out_lo) {
    int t = blockIdx.x;
    const float* xr = x + (size_t)t * DIMC;
    int tid = threadIdx.x;
    float v0 = xr[tid], v1 = xr[tid + 256], v2 = xr[tid + 512];
    __shared__ float red[256];
    red[tid] = v0 + v1 + v2;
    __syncthreads();
    for (int off = 128; off > 0; off >>= 1) {
        if (tid < off) red[tid] += red[tid + off];
        __syncthreads();
    }
    float mu = red[0] * (1.0f / DIMC);
    __syncthreads();
    float d0 = v0 - mu, d1 = v1 - mu, d2 = v2 - mu;
    red[tid] = d0*d0 + d1*d1 + d2*d2;
    __syncthreads();
    for (int off = 128; off > 0; off >>= 1) {
        if (tid < off) red[tid] += red[tid + off];
        __syncthreads();
    }
    float rstd = rsqrtf(red[0] * (1.0f / DIMC) + LN_EPS);
    float o0 = d0 * rstd * g[tid]       + b[tid];
    float o1 = d1 * rstd * g[tid + 256] + b[tid + 256];
    float o2 = d2 * rstd * g[tid + 512] + b[tid + 512];
    if (out_f) {
        float* o = out_f + (size_t)t * DIMC;
        o[tid] = o0; o[tid + 256] = o1; o[tid + 512] = o2;
    }
    if (out_hi) {
        unsigned short* o = out_hi + (size_t)t * DIMC;
        unsigned short h0 = f2bf(o0), h1 = f2bf(o1), h2 = f2bf(o2);
        o[tid] = h0; o[tid + 256] = h1; o[tid + 512] = h2;
        if (out_lo) {
            unsigned short* ol = out_lo + (size_t)t * DIMC;
            ol[tid]       = f2bf(o0 - bf2f(h0));
            ol[tid + 256] = f2bf(o1 - bf2f(h1));
            ol[tid + 512] = f2bf(o2 - bf2f(h2));
        }
    }
}

// ---------------- elementwise fp32 -> bf16 hi/lo split ----------------
__global__ void split_bf16_kernel(const float* __restrict__ src,
                                  unsigned short* __restrict__ dh,
                                  unsigned short* __restrict__ dl, int n4) {
    int i = blockIdx.x * blockDim.x + threadIdx.x;
    if (i >= n4) return;
    float4 v = *(const float4*)(src + (size_t)i * 4);
    ushort4 h, l;
    h.x = f2bf(v.x); l.x = f2bf(v.x - bf2f(h.x));
    h.y = f2bf(v.y); l.y = f2bf(v.y - bf2f(h.y));
    h.z = f2bf(v.z); l.z = f2bf(v.z - bf2f(h.z));
    h.w = f2bf(v.w); l.w = f2bf(v.w - bf2f(h.w));
    *(ushort4*)(dh + (size_t)i * 4) = h;
    *(ushort4*)(dl + (size_t)i * 4) = l;
}

// ---------------- attention: grid (B*H, 7), block 256 (round-3 known-good) ----------------
__global__ void attn_kernel(const float* __restrict__ qkv, float* __restrict__ o) {
    int bh = blockIdx.x;
    int b = bh / HEADS, h = bh % HEADS;
    int i0 = blockIdx.y * 32;
    const float* base = qkv + (size_t)b * NN * 2304;
    __shared__ float qs[32][64];
    __shared__ float ps[32][200];
    int tid = threadIdx.x;
    for (int idx = tid; idx < 32 * 64; idx += 256) {
        int i = idx / 64, d = idx % 64;
        int n = i0 + i;
        qs[i][d] = (n < NN) ? base[(size_t)n * 2304 + h * 64 + d] : 0.f;
    }
    __syncthreads();
    for (int idx = tid; idx < 32 * NN; idx += 256) {
        int i = idx / NN, j = idx % NN;
        const float* kr = base + (size_t)j * 2304 + 768 + h * 64;
        float s = 0.f;
        #pragma unroll
        for (int d = 0; d < 64; ++d) s += qs[i][d] * kr[d];
        ps[i][j] = s * 0.125f;
    }
    __syncthreads();
    {
        int i = tid / 8, l = tid % 8;
        float mx = -1e30f;
        for (int j = l; j < NN; j += 8) mx = fmaxf(mx, ps[i][j]);
        #pragma unroll
        for (int off = 4; off > 0; off >>= 1) mx = fmaxf(mx, __shfl_xor(mx, off, 8));
        float sum = 0.f;
        for (int j = l; j < NN; j += 8) { float e = expf(ps[i][j] - mx); ps[i][j] = e; sum += e; }
        #pragma unroll
        for (int off = 4; off > 0; off >>= 1) sum += __shfl_xor(sum, off, 8);
        float inv = 1.f / sum;
        for (int j = l; j < NN; j += 8) ps[i][j] *= inv;
    }
    __syncthreads();
    for (int idx = tid; idx < 32 * 64; idx += 256) {
        int i = idx / 64, d = idx % 64;
        int n = i0 + i;
        if (n >= NN) continue;
        float s = 0.f;
        for (int j = 0; j < NN; ++j) s += ps[i][j] * base[(size_t)j * 2304 + 1536 + h * 64 + d];
        o[((size_t)(b * NN + n)) * DIMC + h * 64 + d] = s;
    }
}

// ---------------- gate: one wave per token (fp32 — expert choice must match ref) ----------------
__global__ void gate_kernel(const float* __restrict__ xn, const float* __restrict__ gw,
                            int* __restrict__ tok_e, float* __restrict__ tok_g,
                            int* __restrict__ counts) {
    int t = blockIdx.x;
    int lane = threadIdx.x;  // 64
    float acc[8] = {};
    const float* xr = xn + (size_t)t * DIMC;
    for (int i = lane; i < DIMC; i += 64) {
        float xi = xr[i];
        const float* gr = gw + (size_t)i * 8;
        #pragma unroll
        for (int e = 0; e < 8; ++e) acc[e] += xi * gr[e];
    }
    #pragma unroll
    for (int e = 0; e < 8; ++e) {
        #pragma unroll
        for (int off = 32; off > 0; off >>= 1) acc[e] += __shfl_down(acc[e], off, 64);
    }
    if (lane == 0) {
        int e0 = 0; float l0 = acc[0];
        #pragma unroll
        for (int e = 1; e < 8; ++e) if (acc[e] > l0) { l0 = acc[e]; e0 = e; }
        int e1 = -1; float l1 = -3e38f;
        #pragma unroll
        for (int e = 0; e < 8; ++e) if (e != e0 && acc[e] > l1) { l1 = acc[e]; e1 = e; }
        float pp = expf(l1 - l0);
        float g0 = 1.f / (1.f + pp);
        float g1 = pp / (1.f + pp);
        tok_e[t*2] = e0; tok_e[t*2+1] = e1;
        tok_g[t*2] = g0; tok_g[t*2+1] = g1;
        atomicAdd(&counts[e0], 1);
        atomicAdd(&counts[e1], 1);
    }
}

__global__ void init_kernel(int* __restrict__ counts, int* __restrict__ row2tok, int cap) {
    int i = blockIdx.x * blockDim.x + threadIdx.x;
    if (i < 8) counts[i] = 0;
    if (i < cap) row2tok[i] = -1;
}

__global__ void offsets_kernel(const int* __restrict__ counts, int* __restrict__ offsets,
                               int* __restrict__ cursor) {
    if (threadIdx.x == 0 && blockIdx.x == 0) {
        int off = 0;
        for (int e = 0; e < 8; ++e) {
            offsets[e] = off;
            cursor[e]  = off;
            off += ((counts[e] + 63) / 64) * 64;  // pad each segment to BM=64
        }
        offsets[8] = off;
    }
}

__global__ void fill_kernel(const int* __restrict__ tok_e, int* __restrict__ cursor,
                            int* __restrict__ row2tok, int* __restrict__ tok_row) {
    int t = blockIdx.x * blockDim.x + threadIdx.x;
    if (t >= TT) return;
    #pragma unroll
    for (int k = 0; k < 2; ++k) {
        int e = tok_e[t*2+k];
        int slot = atomicAdd(&cursor[e], 1);
        row2tok[slot] = t;
        tok_row[t*2+k] = slot;
    }
}

// ---------------- batched transpose + fp32->bf16: src [B][R][C] -> dst [B][C][R] ----------------
__global__ void transpose_bf16(const float* __restrict__ src, unsigned short* __restrict__ dst,
                               int R, int C) {
    __shared__ float tile[64][65];
    const float* s = src + (size_t)blockIdx.z * R * C;
    unsigned short* d = dst + (size_t)blockIdx.z * R * C;
    int c0 = blockIdx.x * 64, r0 = blockIdx.y * 64;
    int tid = threadIdx.x;
    int tr = tid >> 4;            // 0..15
    int tc = (tid & 15) * 4;      // 0..60
    #pragma unroll
    for (int p = 0; p < 4; ++p) {
        int r = tr + p * 16;
        const float4 v = *(const float4*)(s + (size_t)(r0 + r) * C + c0 + tc);
        tile[r][tc+0] = v.x; tile[r][tc+1] = v.y; tile[r][tc+2] = v.z; tile[r][tc+3] = v.w;
    }
    __syncthreads();
    #pragma unroll
    for (int p = 0; p < 4; ++p) {
        int c = tr + p * 16;      // local col -> dst row
        ushort4 o;
        o.x = f2bf(tile[tc+0][c]);
        o.y = f2bf(tile[tc+1][c]);
        o.z = f2bf(tile[tc+2][c]);
        o.w = f2bf(tile[tc+3][c]);
        *(ushort4*)(d + (size_t)(c0 + c) * R + r0 + tc) = o;
    }
}

// ---------------- transpose + hi/lo split: src [R][C] fp32 -> dh/dl [C][R] bf16 ----------------
__global__ void transpose_split_bf16(const float* __restrict__ src,
                                     unsigned short* __restrict__ dh,
                                     unsigned short* __restrict__ dl, int R, int C) {
    __shared__ float tile[64][65];
    int c0 = blockIdx.x * 64, r0 = blockIdx.y * 64;
    int tid = threadIdx.x;
    int tr = tid >> 4;
    int tc = (tid & 15) * 4;
    #pragma unroll
    for (int p = 0; p < 4; ++p) {
        int r = tr + p * 16;
        const float4 v = *(const float4*)(src + (size_t)(r0 + r) * C + c0 + tc);
        tile[r][tc+0] = v.x; tile[r][tc+1] = v.y; tile[r][tc+2] = v.z; tile[r][tc+3] = v.w;
    }
    __syncthreads();
    #pragma unroll
    for (int p = 0; p < 4; ++p) {
        int c = tr + p * 16;
        ushort4 h, l;
        float v0 = tile[tc+0][c], v1 = tile[tc+1][c], v2 = tile[tc+2][c], v3 = tile[tc+3][c];
        h.x = f2bf(v0); l.x = f2bf(v0 - bf2f(h.x));
        h.y = f2bf(v1); l.y = f2bf(v1 - bf2f(h.y));
        h.z = f2bf(v2); l.z = f2bf(v2 - bf2f(h.z));
        h.w = f2bf(v3); l.w = f2bf(v3 - bf2f(h.w));
        size_t off = (size_t)(c0 + c) * R + r0 + tc;
        *(ushort4*)(dh + off) = h;
        *(ushort4*)(dl + off) = l;
    }
}

// ---------------- split-precision MFMA GEMM: C = (Ah+Al)@(Bh+Bl)^T + bias (+res) ----------------
// A[M][K] as hi/lo bf16 row-major; Bt[N][K] hi/lo bf16. BM=BN=BK=64, 4 waves.
// acc += Ah@Bh + Ah@Bl + Al@Bh  (lo*lo dropped; ~2^-18 relative error => fp32-like)
template<int RES>
__global__ void mfma_gemm_split(const unsigned short* __restrict__ Ah,
                                const unsigned short* __restrict__ Al,
                                const unsigned short* __restrict__ Bth,
                                const unsigned short* __restrict__ Btl,
                                const float* __restrict__ bias,
                                const float* __restrict__ res,
                                float* __restrict__ C,
                                int M, int N, int K) {
    __shared__ unsigned short AsH[64 * 64];
    __shared__ unsigned short AsL[64 * 64];
    __shared__ unsigned short BsH[64 * 64];
    __shared__ unsigned short BsL[64 * 64];

    int m0 = blockIdx.x * 64;
    int n0 = blockIdx.y * 64;
    int tid = threadIdx.x;
    int sr = tid >> 3;        // 0..31
    int sq = tid & 7;         // 16B chunk
    int lane = tid & 63;
    int wid = tid >> 6;
    int wm = (wid >> 1) * 32;
    int wn = (wid & 1) * 32;
    int colb_base = (lane >> 4) * 16;
    int lrow = lane & 15;

    f32x4_t acc[2][2] = {};

    for (int k0 = 0; k0 < K; k0 += 64) {
        #pragma unroll
        for (int p = 0; p < 2; ++p) {
            int r = sr + p * 32;
            int swz = (sq * 16) ^ ((r & 7) << 4);
            int4 vah = {0,0,0,0}, val = {0,0,0,0};
            if (m0 + r < M) {
                size_t aoff = (size_t)(m0 + r) * K + k0 + sq * 8;
                vah = *(const int4*)(Ah + aoff);
                val = *(const int4*)(Al + aoff);
            }
            *(int4*)((char*)AsH + r * 128 + swz) = vah;
            *(int4*)((char*)AsL + r * 128 + swz) = val;
            size_t boff = (size_t)(n0 + r) * K + k0 + sq * 8;
            *(int4*)((char*)BsH + r * 128 + swz) = *(const int4*)(Bth + boff);
            *(int4*)((char*)BsL + r * 128 + swz) = *(const int4*)(Btl + boff);
        }
        __syncthreads();
        #pragma unroll
        for (int kk = 0; kk < 2; ++kk) {
            int colb = kk * 64 + colb_base;
            bf16x8_t ah[2], al[2], bh[2], bl[2];
            #pragma unroll
            for (int i = 0; i < 2; ++i) {
                int ra = wm + i * 16 + lrow;
                int oa = ra * 128 + (colb ^ ((ra & 7) << 4));
                ah[i] = *(const bf16x8_t*)((const char*)AsH + oa);
                al[i] = *(const bf16x8_t*)((const char*)AsL + oa);
                int rb = wn + i * 16 + lrow;
                int ob = rb * 128 + (colb ^ ((rb & 7) << 4));
                bh[i] = *(const bf16x8_t*)((const char*)BsH + ob);
                bl[i] = *(const bf16x8_t*)((const char*)BsL + ob);
            }
            #pragma unroll
            for (int mi = 0; mi < 2; ++mi)
                #pragma unroll
                for (int ni = 0; ni < 2; ++ni) {
                    acc[mi][ni] = __builtin_amdgcn_mfma_f32_16x16x32_bf16(
                        ah[mi], bh[ni], acc[mi][ni], 0, 0, 0);
                    acc[mi][ni] = __builtin_amdgcn_mfma_f32_16x16x32_bf16(
                        ah[mi], bl[ni], acc[mi][ni], 0, 0, 0);
                    acc[mi][ni] = __builtin_amdgcn_mfma_f32_16x16x32_bf16(
                        al[mi], bh[ni], acc[mi][ni], 0, 0, 0);
                }
        }
        __syncthreads();
    }

    #pragma unroll
    for (int mi = 0; mi < 2; ++mi) {
        #pragma unroll
        for (int ni = 0; ni < 2; ++ni) {
            int col = n0 + wn + ni * 16 + lrow;
            #pragma unroll
            for (int j = 0; j < 4; ++j) {
                int row = m0 + wm + mi * 16 + (lane >> 4) * 4 + j;
                if (row < M) {
                    float v = acc[mi][ni][j] + bias[col];
                    if (RES) v += res[(size_t)row * N + col];
                    C[(size_t)row * N + col] = v;
                }
            }
        }
    }
}

// ---------------- grouped bf16 MFMA GEMM (MoE experts; validated rounds 3/5) ----------------
template<int GATHER, int GELU, int OUT_BF16>
__global__ void mfma_gemm_grouped(const unsigned short* __restrict__ A,
                                  const unsigned short* __restrict__ Bt,
                                  const float* __restrict__ bias,
                                  const int* __restrict__ offsets,
                                  const int* __restrict__ row2tok,
                                  void* __restrict__ Cout,
                                  int N, int K) {
    __shared__ unsigned short As[64 * 64];
    __shared__ unsigned short Bs[64 * 64];
    __shared__ int toks[64];

    int r0 = blockIdx.x * 64;
    if (r0 >= offsets[8]) return;
    int e = 0;
    while (r0 >= offsets[e + 1]) ++e;
    int n0 = blockIdx.y * 64;
    int tid = threadIdx.x;
    if (GATHER && tid < 64) toks[tid] = row2tok[r0 + tid];
    __syncthreads();

    const unsigned short* Be = Bt + (size_t)e * N * K;

    int sr = tid >> 3;
    int sq = tid & 7;
    int lane = tid & 63;
    int wid = tid >> 6;
    int wm = (wid >> 1) * 32;
    int wn = (wid & 1) * 32;
    int colb_base = (lane >> 4) * 16;
    int lrow = lane & 15;

    f32x4_t acc[2][2] = {};

    for (int k0 = 0; k0 < K; k0 += 64) {
        #pragma unroll
        for (int p = 0; p < 2; ++p) {
            int r = sr + p * 32;
            int swz = (sq * 16) ^ ((r & 7) << 4);
            int4 va = {0, 0, 0, 0};
            if (GATHER) {
                int tok = toks[r];
                if (tok >= 0) va = *(const int4*)(A + (size_t)tok * K + k0 + sq * 8);
            } else {
                va = *(const int4*)(A + (size_t)(r0 + r) * K + k0 + sq * 8);
            }
            *(int4*)((char*)As + r * 128 + swz) = va;
            int4 vb = *(const int4*)(Be + (size_t)(n0 + r) * K + k0 + sq * 8);
            *(int4*)((char*)Bs + r * 128 + swz) = vb;
        }
        __syncthreads();
        #pragma unroll
        for (int kk = 0; kk < 2; ++kk) {
            int colb = kk * 64 + colb_base;
            bf16x8_t a[2], b[2];
            #pragma unroll
            for (int i = 0; i < 2; ++i) {
                int ra = wm + i * 16 + lrow;
                a[i] = *(const bf16x8_t*)((const char*)As + ra * 128 + (colb ^ ((ra & 7) << 4)));
                int rb = wn + i * 16 + lrow;
                b[i] = *(const bf16x8_t*)((const char*)Bs + rb * 128 + (colb ^ ((rb & 7) << 4)));
            }
            #pragma unroll
            for (int mi = 0; mi < 2; ++mi)
                #pragma unroll
                for (int ni = 0; ni < 2; ++ni)
                    acc[mi][ni] = __builtin_amdgcn_mfma_f32_16x16x32_bf16(
                        a[mi], b[ni], acc[mi][ni], 0, 0, 0);
        }
        __syncthreads();
    }

    #pragma unroll
    for (int mi = 0; mi < 2; ++mi) {
        #pragma unroll
        for (int ni = 0; ni < 2; ++ni) {
            int col = n0 + wn + ni * 16 + lrow;
            float bv = GELU ? bias[(size_t)e * N + col] : 0.f;
            #pragma unroll
            for (int j = 0; j < 4; ++j) {
                int row = r0 + wm + mi * 16 + (lane >> 4) * 4 + j;
                float v = acc[mi][ni][j] + bv;
                if (GELU) v = 0.5f * v * (1.f + erff(v * 0.70710678f));
                if (OUT_BF16)
                    ((unsigned short*)Cout)[(size_t)row * N + col] = f2bf(v);
                else
                    ((float*)Cout)[(size_t)row * N + col] = v;
            }
        }
    }
}

// ---------------- combine: out = x_res + sum_k g_k*(y[row_k] + b2[e_k]) ----------------
__global__ void combine_kernel(const float* __restrict__ x_res, const float* __restrict__ y,
                               const float* __restrict__ b2, const int* __restrict__ tok_e,
                               const float* __restrict__ tok_g, const int* __restrict__ tok_row,
                               float* __restrict__ out) {
    int t = blockIdx.x;
    int c = blockIdx.y * 256 + threadIdx.x;
    int e0 = tok_e[t*2], e1 = tok_e[t*2+1];
    float g0 = tok_g[t*2], g1 = tok_g[t*2+1];
    int r0 = tok_row[t*2], r1 = tok_row[t*2+1];
    float v = x_res[(size_t)t * DIMC + c]
            + g0 * (y[(size_t)r0 * DIMC + c] + b2[(size_t)e0 * DIMC + c])
            + g1 * (y[(size_t)r1 * DIMC + c] + b2[(size_t)e1 * DIMC + c]);
    out[(size_t)t * DIMC + c] = v;
}

extern "C" void kernel_launch(void* const* d_in, const int* in_sizes, int n_in,
                              void* d_out, int out_size, void* d_ws, size_t ws_size,
                              hipStream_t stream) {
    const float* x      = (const float*)d_in[0];
    const float* ln1_g  = (const float*)d_in[1];
    const float* ln1_b  = (const float*)d_in[2];
    const float* qkv_w  = (const float*)d_in[3];
    const float* qkv_b  = (const float*)d_in[4];
    const float* proj_w = (const float*)d_in[5];
    const float* proj_b = (const float*)d_in[6];
    const float* ln2_g  = (const float*)d_in[7];
    const float* ln2_b  = (const float*)d_in[8];
    const float* gate_w = (const float*)d_in[9];
    const float* w1     = (const float*)d_in[10];
    const float* b1     = (const float*)d_in[11];
    const float* w2     = (const float*)d_in[12];
    const float* b2     = (const float*)d_in[13];
    float* out = (float*)d_out;

    char* p = (char*)d_ws;
    auto alloc = [&](size_t nbytes) {
        void* r = (void*)p;
        p += (nbytes + 255) & ~(size_t)255;
        return r;
    };
    unsigned short* xn1_h   = (unsigned short*)alloc((size_t)TT * DIMC * 2);
    unsigned short* xn1_l   = (unsigned short*)alloc((size_t)TT * DIMC * 2);
    float*          qkv     = (float*)alloc((size_t)TT * 2304 * 4);
    float*          attn_o  = (float*)alloc((size_t)TT * DIMC * 4);
    unsigned short* ao_h    = (unsigned short*)alloc((size_t)TT * DIMC * 2);
    unsigned short* ao_l    = (unsigned short*)alloc((size_t)TT * DIMC * 2);
    float*          x_res   = (float*)alloc((size_t)TT * DIMC * 4);
    float*          xn2_f   = (float*)alloc((size_t)TT * DIMC * 4);
    unsigned short* xn2_bf  = (unsigned short*)alloc((size_t)TT * DIMC * 2);
    unsigned short* h       = (unsigned short*)alloc((size_t)CAP_ROWS * HID * 2);
    float*          y       = (float*)alloc((size_t)CAP_ROWS * DIMC * 4);
    unsigned short* w1t     = (unsigned short*)alloc((size_t)EXPERTS * DIMC * HID * 2);
    unsigned short* w2t     = (unsigned short*)alloc((size_t)EXPERTS * DIMC * HID * 2);
    unsigned short* qwt_h   = (unsigned short*)alloc((size_t)DIMC * 2304 * 2);
    unsigned short* qwt_l   = (unsigned short*)alloc((size_t)DIMC * 2304 * 2);
    unsigned short* pwt_h   = (unsigned short*)alloc((size_t)DIMC * DIMC * 2);
    unsigned short* pwt_l   = (unsigned short*)alloc((size_t)DIMC * DIMC * 2);
    float*          tok_g   = (float*)alloc((size_t)2 * TT * 4);
    int*            tok_e   = (int*)alloc((size_t)2 * TT * 4);
    int*            tok_row = (int*)alloc((size_t)2 * TT * 4);
    int*            row2tok = (int*)alloc((size_t)CAP_ROWS * 4);
    int*            counts  = (int*)alloc(32 * 4);
    int*            offsets = (int*)alloc(32 * 4);
    int*            cursor  = (int*)alloc(32 * 4);

    init_kernel<<<(CAP_ROWS + 255) / 256, 256, 0, stream>>>(counts, row2tok, CAP_ROWS);

    // weight transposes (independent of activations)
    transpose_bf16<<<dim3(HID / 64, DIMC / 64, EXPERTS), 256, 0, stream>>>(w1, w1t, DIMC, HID);
    transpose_bf16<<<dim3(DIMC / 64, HID / 64, EXPERTS), 256, 0, stream>>>(w2, w2t, HID, DIMC);
    transpose_split_bf16<<<dim3(2304 / 64, DIMC / 64), 256, 0, stream>>>(qkv_w, qwt_h, qwt_l,
                                                                         DIMC, 2304);
    transpose_split_bf16<<<dim3(DIMC / 64, DIMC / 64), 256, 0, stream>>>(proj_w, pwt_h, pwt_l,
                                                                         DIMC, DIMC);

    ln_kernel<<<TT, 256, 0, stream>>>(x, ln1_g, ln1_b, nullptr, xn1_h, xn1_l);

    mfma_gemm_split<0><<<dim3((TT + 63) / 64, 2304 / 64), 256, 0, stream>>>(
        xn1_h, xn1_l, qwt_h, qwt_l, qkv_b, nullptr, qkv, TT, 2304, DIMC);

    attn_kernel<<<dim3(BB * HEADS, (NN + 31) / 32), 256, 0, stream>>>(qkv, attn_o);

    split_bf16_kernel<<<(TT * DIMC / 4 + 255) / 256, 256, 0, stream>>>(
        attn_o, ao_h, ao_l, TT * DIMC / 4);

    mfma_gemm_split<1><<<dim3((TT + 63) / 64, DIMC / 64), 256, 0, stream>>>(
        ao_h, ao_l, pwt_h, pwt_l, proj_b, x, x_res, TT, DIMC, DIMC);

    ln_kernel<<<TT, 256, 0, stream>>>(x_res, ln2_g, ln2_b, xn2_f, xn2_bf, nullptr);

    gate_kernel<<<TT, 64, 0, stream>>>(xn2_f, gate_w, tok_e, tok_g, counts);

    offsets_kernel<<<1, 64, 0, stream>>>(counts, offsets, cursor);

    fill_kernel<<<(TT + 255) / 256, 256, 0, stream>>>(tok_e, cursor, row2tok, tok_row);

    mfma_gemm_grouped<1, 1, 1><<<dim3(CAP_ROWS / 64, HID / 64), 256, 0, stream>>>(
        xn2_bf, w1t, b1, offsets, row2tok, h, HID, DIMC);

    mfma_gemm_grouped<0, 0, 0><<<dim3(CAP_ROWS / 64, DIMC / 64), 256, 0, stream>>>(
        h, w2t, nullptr, offsets, row2tok, y, DIMC, HID);

    combine_kernel<<<dim3(TT, 3), 256, 0, stream>>>(x_res, y, b2, tok_e, tok_g, tok_row, out);
}

// Round 7
// 337.592 us; speedup vs baseline: 2.5581x; 1.5806x over previous
//
#include <hip/hip_runtime.h>
#include <hip/hip_bf16.h>
#include <math.h>

#define DIMC 768
#define HEADS 12
#define HD 64
#define EXPERTS 8
#define HID 3072
#define BB 8
#define NN 196
#define TT (BB*NN)      // 1568
#define CAP_ROWS 3648   // 2*TT + 8*64 headroom, multiple of 64
#define LN_EPS 1e-5f

typedef float f32x4_t __attribute__((ext_vector_type(4)));
typedef short bf16x8_t __attribute__((ext_vector_type(8)));
typedef unsigned short u16x8_t __attribute__((ext_vector_type(8)));

__device__ __forceinline__ unsigned short f2bf(float f) {
    unsigned int u = __float_as_uint(f);
    u += 0x7FFFu + ((u >> 16) & 1u);   // round-to-nearest-even
    return (unsigned short)(u >> 16);
}
__device__ __forceinline__ float bf2f(unsigned short u) {
    return __uint_as_float(((unsigned int)u) << 16);
}

// ---------------- LayerNorm: one block per token, 256 threads, D=768 ----------------
__global__ void ln_kernel(const float* __restrict__ x, const float* __restrict__ g,
                          const float* __restrict__ b, float* __restrict__ out_f,
                          unsigned short* __restrict__ out_hi,
                          unsigned short* __restrict__ out_lo) {
    int t = blockIdx.x;
    const float* xr = x + (size_t)t * DIMC;
    int tid = threadIdx.x;
    float v0 = xr[tid], v1 = xr[tid + 256], v2 = xr[tid + 512];
    __shared__ float red[256];
    red[tid] = v0 + v1 + v2;
    __syncthreads();
    for (int off = 128; off > 0; off >>= 1) {
        if (tid < off) red[tid] += red[tid + off];
        __syncthreads();
    }
    float mu = red[0] * (1.0f / DIMC);
    __syncthreads();
    float d0 = v0 - mu, d1 = v1 - mu, d2 = v2 - mu;
    red[tid] = d0*d0 + d1*d1 + d2*d2;
    __syncthreads();
    for (int off = 128; off > 0; off >>= 1) {
        if (tid < off) red[tid] += red[tid + off];
        __syncthreads();
    }
    float rstd = rsqrtf(red[0] * (1.0f / DIMC) + LN_EPS);
    float o0 = d0 * rstd * g[tid]       + b[tid];
    float o1 = d1 * rstd * g[tid + 256] + b[tid + 256];
    float o2 = d2 * rstd * g[tid + 512] + b[tid + 512];
    if (out_f) {
        float* o = out_f + (size_t)t * DIMC;
        o[tid] = o0; o[tid + 256] = o1; o[tid + 512] = o2;
    }
    if (out_hi) {
        unsigned short* o = out_hi + (size_t)t * DIMC;
        unsigned short h0 = f2bf(o0), h1 = f2bf(o1), h2 = f2bf(o2);
        o[tid] = h0; o[tid + 256] = h1; o[tid + 512] = h2;
        if (out_lo) {
            unsigned short* ol = out_lo + (size_t)t * DIMC;
            ol[tid]       = f2bf(o0 - bf2f(h0));
            ol[tid + 256] = f2bf(o1 - bf2f(h1));
            ol[tid + 512] = f2bf(o2 - bf2f(h2));
        }
    }
}

// ---------------- MFMA attention, split-precision (fp32-accurate) ----------------
// grid (B*H, 4): one block per (b,h, 64-row q-tile). 256 threads = 4 waves.
// Follows the validated mfma_gemm staging/swizzle/fragment/C-layout idioms.
__global__ void attn_mfma_kernel(const float* __restrict__ qkv,
                                 unsigned short* __restrict__ ao_h,
                                 unsigned short* __restrict__ ao_l) {
    __shared__ float ps[64][224];                         // S then P, fp32 (57.3 KB)
    __shared__ unsigned short QsH[64 * 64], QsL[64 * 64]; // Q hi/lo (8 KB each)
    __shared__ unsigned short KsH[64 * 64], KsL[64 * 64]; // K tile; reused as V^T tile

    int bh = blockIdx.x;
    int b = bh / HEADS, h = bh % HEADS;
    int q0 = blockIdx.y * 64;
    const float* base = qkv + (size_t)b * NN * 2304 + h * 64;

    int tid = threadIdx.x;
    int sr = tid >> 3, sq = tid & 7;   // staging: row, 8-elem chunk
    int lane = tid & 63;
    int wid = tid >> 6;
    int wm = (wid >> 1) * 32;
    int wn = (wid & 1) * 32;
    int lrow = lane & 15;
    int lq = lane >> 4;                // 0..3
    int colb_base = lq * 16;

    // ---- stage Q-tile hi/lo (zero-pad rows >= NN) ----
    #pragma unroll
    for (int p = 0; p < 2; ++p) {
        int r = sr + p * 32;
        int n = q0 + r;
        float v[8] = {0.f,0.f,0.f,0.f,0.f,0.f,0.f,0.f};
        if (n < NN) {
            float4 a0 = *(const float4*)(base + (size_t)n * 2304 + sq * 8);
            float4 a1 = *(const float4*)(base + (size_t)n * 2304 + sq * 8 + 4);
            v[0]=a0.x; v[1]=a0.y; v[2]=a0.z; v[3]=a0.w;
            v[4]=a1.x; v[5]=a1.y; v[6]=a1.z; v[7]=a1.w;
        }
        u16x8_t hv, lv;
        #pragma unroll
        for (int t = 0; t < 8; ++t) {
            unsigned short hh = f2bf(v[t]);
            hv[t] = hh; lv[t] = f2bf(v[t] - bf2f(hh));
        }
        int off = r * 128 + ((sq * 16) ^ ((r & 7) << 4));
        *(u16x8_t*)((char*)QsH + off) = hv;
        *(u16x8_t*)((char*)QsL + off) = lv;
    }

    // ---- S = scale * Q K^T over 4 K-tiles ----
    for (int kt = 0; kt < 4; ++kt) {
        int j0 = kt * 64;
        __syncthreads();   // previous-tile fragment reads done before restaging
        #pragma unroll
        for (int p = 0; p < 2; ++p) {
            int r = sr + p * 32;
            int n = j0 + r;
            float v[8] = {0.f,0.f,0.f,0.f,0.f,0.f,0.f,0.f};
            if (n < NN) {
                float4 a0 = *(const float4*)(base + (size_t)n * 2304 + 768 + sq * 8);
                float4 a1 = *(const float4*)(base + (size_t)n * 2304 + 768 + sq * 8 + 4);
                v[0]=a0.x; v[1]=a0.y; v[2]=a0.z; v[3]=a0.w;
                v[4]=a1.x; v[5]=a1.y; v[6]=a1.z; v[7]=a1.w;
            }
            u16x8_t hv, lv;
            #pragma unroll
            for (int t = 0; t < 8; ++t) {
                unsigned short hh = f2bf(v[t]);
                hv[t] = hh; lv[t] = f2bf(v[t] - bf2f(hh));
            }
            int off = r * 128 + ((sq * 16) ^ ((r & 7) << 4));
            *(u16x8_t*)((char*)KsH + off) = hv;
            *(u16x8_t*)((char*)KsL + off) = lv;
        }
        __syncthreads();   // covers Q (first iter) + K staging

        f32x4_t acc[2][2] = {};
        #pragma unroll
        for (int kk = 0; kk < 2; ++kk) {
            int colb = kk * 64 + colb_base;
            bf16x8_t qh[2], ql[2], kh[2], kl[2];
            #pragma unroll
            for (int i = 0; i < 2; ++i) {
                int ra = wm + i * 16 + lrow;
                int oa = ra * 128 + (colb ^ ((ra & 7) << 4));
                qh[i] = *(const bf16x8_t*)((const char*)QsH + oa);
                ql[i] = *(const bf16x8_t*)((const char*)QsL + oa);
                int rb = wn + i * 16 + lrow;
                int ob = rb * 128 + (colb ^ ((rb & 7) << 4));
                kh[i] = *(const bf16x8_t*)((const char*)KsH + ob);
                kl[i] = *(const bf16x8_t*)((const char*)KsL + ob);
            }
            #pragma unroll
            for (int mi = 0; mi < 2; ++mi)
                #pragma unroll
                for (int ni = 0; ni < 2; ++ni) {
                    acc[mi][ni] = __builtin_amdgcn_mfma_f32_16x16x32_bf16(
                        qh[mi], kh[ni], acc[mi][ni], 0, 0, 0);
                    acc[mi][ni] = __builtin_amdgcn_mfma_f32_16x16x32_bf16(
                        qh[mi], kl[ni], acc[mi][ni], 0, 0, 0);
                    acc[mi][ni] = __builtin_amdgcn_mfma_f32_16x16x32_bf16(
                        ql[mi], kh[ni], acc[mi][ni], 0, 0, 0);
                }
        }
        // write S tile (C-layout as validated): col=lane&15, row=(lane>>4)*4+j
        #pragma unroll
        for (int mi = 0; mi < 2; ++mi)
            #pragma unroll
            for (int ni = 0; ni < 2; ++ni) {
                int jc = j0 + wn + ni * 16 + lrow;
                if (jc < 224) {
                    int rowb = wm + mi * 16 + lq * 4;
                    #pragma unroll
                    for (int j = 0; j < 4; ++j)
                        ps[rowb + j][jc] = acc[mi][ni][j] * 0.125f;
                }
            }
    }
    __syncthreads();

    // ---- softmax over j<NN (4 threads per row) ----
    {
        int i = tid >> 2, l = tid & 3;
        float mx = -1e30f;
        for (int j = l; j < NN; j += 4) mx = fmaxf(mx, ps[i][j]);
        mx = fmaxf(mx, __shfl_xor(mx, 1, 4));
        mx = fmaxf(mx, __shfl_xor(mx, 2, 4));
        float sum = 0.f;
        for (int j = l; j < NN; j += 4) { float e = expf(ps[i][j] - mx); ps[i][j] = e; sum += e; }
        sum += __shfl_xor(sum, 1, 4);
        sum += __shfl_xor(sum, 2, 4);
        float inv = 1.f / sum;
        for (int j = l; j < NN; j += 4) ps[i][j] *= inv;
    }

    // ---- O = P V over 4 V-tiles (V staged transposed hi/lo into Ks buffers) ----
    f32x4_t oacc[2][2] = {};
    for (int kt = 0; kt < 4; ++kt) {
        int j0 = kt * 64;
        __syncthreads();   // softmax done (kt=0) / prev fragment reads done
        #pragma unroll
        for (int p = 0; p < 2; ++p) {
            int r = sr + p * 32;           // j within tile
            int n = j0 + r;
            float v[8] = {0.f,0.f,0.f,0.f,0.f,0.f,0.f,0.f};
            if (n < NN) {
                float4 a0 = *(const float4*)(base + (size_t)n * 2304 + 1536 + sq * 8);
                float4 a1 = *(const float4*)(base + (size_t)n * 2304 + 1536 + sq * 8 + 4);
                v[0]=a0.x; v[1]=a0.y; v[2]=a0.z; v[3]=a0.w;
                v[4]=a1.x; v[5]=a1.y; v[6]=a1.z; v[7]=a1.w;
            }
            #pragma unroll
            for (int t = 0; t < 8; ++t) {
                int d = sq * 8 + t;
                unsigned short hh = f2bf(v[t]);
                int off = d * 128 + ((r * 2) ^ ((d & 7) << 4));
                *(unsigned short*)((char*)KsH + off) = hh;
                *(unsigned short*)((char*)KsL + off) = f2bf(v[t] - bf2f(hh));
            }
        }
        __syncthreads();

        int kkmax = (kt == 3) ? 1 : 2;
        for (int kk = 0; kk < kkmax; ++kk) {
            int colb = kk * 64 + colb_base;
            bf16x8_t pah[2], pal[2], vh[2], vl[2];
            #pragma unroll
            for (int i = 0; i < 2; ++i) {
                int ra = wm + i * 16 + lrow;
                const float* prow = &ps[ra][j0 + kk * 32 + lq * 8];
                float4 a0 = *(const float4*)prow;
                float4 a1 = *(const float4*)(prow + 4);
                float vv[8] = {a0.x,a0.y,a0.z,a0.w,a1.x,a1.y,a1.z,a1.w};
                u16x8_t hv, lv;
                #pragma unroll
                for (int t = 0; t < 8; ++t) {
                    unsigned short hh = f2bf(vv[t]);
                    hv[t] = hh; lv[t] = f2bf(vv[t] - bf2f(hh));
                }
                pah[i] = *(bf16x8_t*)&hv;
                pal[i] = *(bf16x8_t*)&lv;
                int rb = wn + i * 16 + lrow;
                int ob = rb * 128 + (colb ^ ((rb & 7) << 4));
                vh[i] = *(const bf16x8_t*)((const char*)KsH + ob);
                vl[i] = *(const bf16x8_t*)((const char*)KsL + ob);
            }
            #pragma unroll
            for (int mi = 0; mi < 2; ++mi)
                #pragma unroll
                for (int ni = 0; ni < 2; ++ni) {
                    oacc[mi][ni] = __builtin_amdgcn_mfma_f32_16x16x32_bf16(
                        pah[mi], vh[ni], oacc[mi][ni], 0, 0, 0);
                    oacc[mi][ni] = __builtin_amdgcn_mfma_f32_16x16x32_bf16(
                        pah[mi], vl[ni], oacc[mi][ni], 0, 0, 0);
                    oacc[mi][ni] = __builtin_amdgcn_mfma_f32_16x16x32_bf16(
                        pal[mi], vh[ni], oacc[mi][ni], 0, 0, 0);
                }
        }
    }

    // ---- epilogue: write O directly as bf16 hi/lo (feeds split proj GEMM) ----
    #pragma unroll
    for (int mi = 0; mi < 2; ++mi)
        #pragma unroll
        for (int ni = 0; ni < 2; ++ni) {
            int col = h * 64 + wn + ni * 16 + lrow;
            #pragma unroll
            for (int j = 0; j < 4; ++j) {
                int n = q0 + wm + mi * 16 + lq * 4 + j;
                if (n < NN) {
                    float v = oacc[mi][ni][j];
                    unsigned short hh = f2bf(v);
                    size_t o = (size_t)(b * NN + n) * DIMC + col;
                    ao_h[o] = hh;
                    ao_l[o] = f2bf(v - bf2f(hh));
                }
            }
        }
}

// ---------------- gate: one wave per token (fp32 — expert choice must match ref) ----------------
__global__ void gate_kernel(const float* __restrict__ xn, const float* __restrict__ gw,
                            int* __restrict__ tok_e, float* __restrict__ tok_g,
                            int* __restrict__ counts) {
    int t = blockIdx.x;
    int lane = threadIdx.x;  // 64
    float acc[8] = {};
    const float* xr = xn + (size_t)t * DIMC;
    for (int i = lane; i < DIMC; i += 64) {
        float xi = xr[i];
        const float* gr = gw + (size_t)i * 8;
        #pragma unroll
        for (int e = 0; e < 8; ++e) acc[e] += xi * gr[e];
    }
    #pragma unroll
    for (int e = 0; e < 8; ++e) {
        #pragma unroll
        for (int off = 32; off > 0; off >>= 1) acc[e] += __shfl_down(acc[e], off, 64);
    }
    if (lane == 0) {
        int e0 = 0; float l0 = acc[0];
        #pragma unroll
        for (int e = 1; e < 8; ++e) if (acc[e] > l0) { l0 = acc[e]; e0 = e; }
        int e1 = -1; float l1 = -3e38f;
        #pragma unroll
        for (int e = 0; e < 8; ++e) if (e != e0 && acc[e] > l1) { l1 = acc[e]; e1 = e; }
        float pp = expf(l1 - l0);
        float g0 = 1.f / (1.f + pp);
        float g1 = pp / (1.f + pp);
        tok_e[t*2] = e0; tok_e[t*2+1] = e1;
        tok_g[t*2] = g0; tok_g[t*2+1] = g1;
        atomicAdd(&counts[e0], 1);
        atomicAdd(&counts[e1], 1);
    }
}

__global__ void init_kernel(int* __restrict__ counts, int* __restrict__ row2tok, int cap) {
    int i = blockIdx.x * blockDim.x + threadIdx.x;
    if (i < 8) counts[i] = 0;
    if (i < cap) row2tok[i] = -1;
}

__global__ void offsets_kernel(const int* __restrict__ counts, int* __restrict__ offsets,
                               int* __restrict__ cursor) {
    if (threadIdx.x == 0 && blockIdx.x == 0) {
        int off = 0;
        for (int e = 0; e < 8; ++e) {
            offsets[e] = off;
            cursor[e]  = off;
            off += ((counts[e] + 63) / 64) * 64;  // pad each segment to BM=64
        }
        offsets[8] = off;
    }
}

__global__ void fill_kernel(const int* __restrict__ tok_e, int* __restrict__ cursor,
                            int* __restrict__ row2tok, int* __restrict__ tok_row) {
    int t = blockIdx.x * blockDim.x + threadIdx.x;
    if (t >= TT) return;
    #pragma unroll
    for (int k = 0; k < 2; ++k) {
        int e = tok_e[t*2+k];
        int slot = atomicAdd(&cursor[e], 1);
        row2tok[slot] = t;
        tok_row[t*2+k] = slot;
    }
}

// ---------------- batched transpose + fp32->bf16: src [B][R][C] -> dst [B][C][R] ----------------
__global__ void transpose_bf16(const float* __restrict__ src, unsigned short* __restrict__ dst,
                               int R, int C) {
    __shared__ float tile[64][65];
    const float* s = src + (size_t)blockIdx.z * R * C;
    unsigned short* d = dst + (size_t)blockIdx.z * R * C;
    int c0 = blockIdx.x * 64, r0 = blockIdx.y * 64;
    int tid = threadIdx.x;
    int tr = tid >> 4;            // 0..15
    int tc = (tid & 15) * 4;      // 0..60
    #pragma unroll
    for (int p = 0; p < 4; ++p) {
        int r = tr + p * 16;
        const float4 v = *(const float4*)(s + (size_t)(r0 + r) * C + c0 + tc);
        tile[r][tc+0] = v.x; tile[r][tc+1] = v.y; tile[r][tc+2] = v.z; tile[r][tc+3] = v.w;
    }
    __syncthreads();
    #pragma unroll
    for (int p = 0; p < 4; ++p) {
        int c = tr + p * 16;      // local col -> dst row
        ushort4 o;
        o.x = f2bf(tile[tc+0][c]);
        o.y = f2bf(tile[tc+1][c]);
        o.z = f2bf(tile[tc+2][c]);
        o.w = f2bf(tile[tc+3][c]);
        *(ushort4*)(d + (size_t)(c0 + c) * R + r0 + tc) = o;
    }
}

// ---------------- transpose + hi/lo split: src [R][C] fp32 -> dh/dl [C][R] bf16 ----------------
__global__ void transpose_split_bf16(const float* __restrict__ src,
                                     unsigned short* __restrict__ dh,
                                     unsigned short* __restrict__ dl, int R, int C) {
    __shared__ float tile[64][65];
    int c0 = blockIdx.x * 64, r0 = blockIdx.y * 64;
    int tid = threadIdx.x;
    int tr = tid >> 4;
    int tc = (tid & 15) * 4;
    #pragma unroll
    for (int p = 0; p < 4; ++p) {
        int r = tr + p * 16;
        const float4 v = *(const float4*)(src + (size_t)(r0 + r) * C + c0 + tc);
        tile[r][tc+0] = v.x; tile[r][tc+1] = v.y; tile[r][tc+2] = v.z; tile[r][tc+3] = v.w;
    }
    __syncthreads();
    #pragma unroll
    for (int p = 0; p < 4; ++p) {
        int c = tr + p * 16;
        ushort4 h, l;
        float v0 = tile[tc+0][c], v1 = tile[tc+1][c], v2 = tile[tc+2][c], v3 = tile[tc+3][c];
        h.x = f2bf(v0); l.x = f2bf(v0 - bf2f(h.x));
        h.y = f2bf(v1); l.y = f2bf(v1 - bf2f(h.y));
        h.z = f2bf(v2); l.z = f2bf(v2 - bf2f(h.z));
        h.w = f2bf(v3); l.w = f2bf(v3 - bf2f(h.w));
        size_t off = (size_t)(c0 + c) * R + r0 + tc;
        *(ushort4*)(dh + off) = h;
        *(ushort4*)(dl + off) = l;
    }
}

// ---------------- split-precision MFMA GEMM: C = (Ah+Al)@(Bh+Bl)^T + bias (+res) ----------------
template<int RES>
__global__ void mfma_gemm_split(const unsigned short* __restrict__ Ah,
                                const unsigned short* __restrict__ Al,
                                const unsigned short* __restrict__ Bth,
                                const unsigned short* __restrict__ Btl,
                                const float* __restrict__ bias,
                                const float* __restrict__ res,
                                float* __restrict__ C,
                                int M, int N, int K) {
    __shared__ unsigned short AsH[64 * 64];
    __shared__ unsigned short AsL[64 * 64];
    __shared__ unsigned short BsH[64 * 64];
    __shared__ unsigned short BsL[64 * 64];

    int m0 = blockIdx.x * 64;
    int n0 = blockIdx.y * 64;
    int tid = threadIdx.x;
    int sr = tid >> 3;
    int sq = tid & 7;
    int lane = tid & 63;
    int wid = tid >> 6;
    int wm = (wid >> 1) * 32;
    int wn = (wid & 1) * 32;
    int colb_base = (lane >> 4) * 16;
    int lrow = lane & 15;

    f32x4_t acc[2][2] = {};

    for (int k0 = 0; k0 < K; k0 += 64) {
        #pragma unroll
        for (int p = 0; p < 2; ++p) {
            int r = sr + p * 32;
            int swz = (sq * 16) ^ ((r & 7) << 4);
            int4 vah = {0,0,0,0}, val = {0,0,0,0};
            if (m0 + r < M) {
                size_t aoff = (size_t)(m0 + r) * K + k0 + sq * 8;
                vah = *(const int4*)(Ah + aoff);
                val = *(const int4*)(Al + aoff);
            }
            *(int4*)((char*)AsH + r * 128 + swz) = vah;
            *(int4*)((char*)AsL + r * 128 + swz) = val;
            size_t boff = (size_t)(n0 + r) * K + k0 + sq * 8;
            *(int4*)((char*)BsH + r * 128 + swz) = *(const int4*)(Bth + boff);
            *(int4*)((char*)BsL + r * 128 + swz) = *(const int4*)(Btl + boff);
        }
        __syncthreads();
        #pragma unroll
        for (int kk = 0; kk < 2; ++kk) {
            int colb = kk * 64 + colb_base;
            bf16x8_t ah[2], al[2], bh[2], bl[2];
            #pragma unroll
            for (int i = 0; i < 2; ++i) {
                int ra = wm + i * 16 + lrow;
                int oa = ra * 128 + (colb ^ ((ra & 7) << 4));
                ah[i] = *(const bf16x8_t*)((const char*)AsH + oa);
                al[i] = *(const bf16x8_t*)((const char*)AsL + oa);
                int rb = wn + i * 16 + lrow;
                int ob = rb * 128 + (colb ^ ((rb & 7) << 4));
                bh[i] = *(const bf16x8_t*)((const char*)BsH + ob);
                bl[i] = *(const bf16x8_t*)((const char*)BsL + ob);
            }
            #pragma unroll
            for (int mi = 0; mi < 2; ++mi)
                #pragma unroll
                for (int ni = 0; ni < 2; ++ni) {
                    acc[mi][ni] = __builtin_amdgcn_mfma_f32_16x16x32_bf16(
                        ah[mi], bh[ni], acc[mi][ni], 0, 0, 0);
                    acc[mi][ni] = __builtin_amdgcn_mfma_f32_16x16x32_bf16(
                        ah[mi], bl[ni], acc[mi][ni], 0, 0, 0);
                    acc[mi][ni] = __builtin_amdgcn_mfma_f32_16x16x32_bf16(
                        al[mi], bh[ni], acc[mi][ni], 0, 0, 0);
                }
        }
        __syncthreads();
    }

    #pragma unroll
    for (int mi = 0; mi < 2; ++mi) {
        #pragma unroll
        for (int ni = 0; ni < 2; ++ni) {
            int col = n0 + wn + ni * 16 + lrow;
            #pragma unroll
            for (int j = 0; j < 4; ++j) {
                int row = m0 + wm + mi * 16 + (lane >> 4) * 4 + j;
                if (row < M) {
                    float v = acc[mi][ni][j] + bias[col];
                    if (RES) v += res[(size_t)row * N + col];
                    C[(size_t)row * N + col] = v;
                }
            }
        }
    }
}

// ---------------- grouped bf16 MFMA GEMM (MoE experts; validated) ----------------
template<int GATHER, int GELU, int OUT_BF16>
__global__ void mfma_gemm_grouped(const unsigned short* __restrict__ A,
                                  const unsigned short* __restrict__ Bt,
                                  const float* __restrict__ bias,
                                  const int* __restrict__ offsets,
                                  const int* __restrict__ row2tok,
                                  void* __restrict__ Cout,
                                  int N, int K) {
    __shared__ unsigned short As[64 * 64];
    __shared__ unsigned short Bs[64 * 64];
    __shared__ int toks[64];

    int r0 = blockIdx.x * 64;
    if (r0 >= offsets[8]) return;
    int e = 0;
    while (r0 >= offsets[e + 1]) ++e;
    int n0 = blockIdx.y * 64;
    int tid = threadIdx.x;
    if (GATHER && tid < 64) toks[tid] = row2tok[r0 + tid];
    __syncthreads();

    const unsigned short* Be = Bt + (size_t)e * N * K;

    int sr = tid >> 3;
    int sq = tid & 7;
    int lane = tid & 63;
    int wid = tid >> 6;
    int wm = (wid >> 1) * 32;
    int wn = (wid & 1) * 32;
    int colb_base = (lane >> 4) * 16;
    int lrow = lane & 15;

    f32x4_t acc[2][2] = {};

    for (int k0 = 0; k0 < K; k0 += 64) {
        #pragma unroll
        for (int p = 0; p < 2; ++p) {
            int r = sr + p * 32;
            int swz = (sq * 16) ^ ((r & 7) << 4);
            int4 va = {0, 0, 0, 0};
            if (GATHER) {
                int tok = toks[r];
                if (tok >= 0) va = *(const int4*)(A + (size_t)tok * K + k0 + sq * 8);
            } else {
                va = *(const int4*)(A + (size_t)(r0 + r) * K + k0 + sq * 8);
            }
            *(int4*)((char*)As + r * 128 + swz) = va;
            int4 vb = *(const int4*)(Be + (size_t)(n0 + r) * K + k0 + sq * 8);
            *(int4*)((char*)Bs + r * 128 + swz) = vb;
        }
        __syncthreads();
        #pragma unroll
        for (int kk = 0; kk < 2; ++kk) {
            int colb = kk * 64 + colb_base;
            bf16x8_t a[2], b[2];
            #pragma unroll
            for (int i = 0; i < 2; ++i) {
                int ra = wm + i * 16 + lrow;
                a[i] = *(const bf16x8_t*)((const char*)As + ra * 128 + (colb ^ ((ra & 7) << 4)));
                int rb = wn + i * 16 + lrow;
                b[i] = *(const bf16x8_t*)((const char*)Bs + rb * 128 + (colb ^ ((rb & 7) << 4)));
            }
            #pragma unroll
            for (int mi = 0; mi < 2; ++mi)
                #pragma unroll
                for (int ni = 0; ni < 2; ++ni)
                    acc[mi][ni] = __builtin_amdgcn_mfma_f32_16x16x32_bf16(
                        a[mi], b[ni], acc[mi][ni], 0, 0, 0);
        }
        __syncthreads();
    }

    #pragma unroll
    for (int mi = 0; mi < 2; ++mi) {
        #pragma unroll
        for (int ni = 0; ni < 2; ++ni) {
            int col = n0 + wn + ni * 16 + lrow;
            float bv = GELU ? bias[(size_t)e * N + col] : 0.f;
            #pragma unroll
            for (int j = 0; j < 4; ++j) {
                int row = r0 + wm + mi * 16 + (lane >> 4) * 4 + j;
                float v = acc[mi][ni][j] + bv;
                if (GELU) v = 0.5f * v * (1.f + erff(v * 0.70710678f));
                if (OUT_BF16)
                    ((unsigned short*)Cout)[(size_t)row * N + col] = f2bf(v);
                else
                    ((float*)Cout)[(size_t)row * N + col] = v;
            }
        }
    }
}

// ---------------- combine: out = x_res + sum_k g_k*(y[row_k] + b2[e_k]) ----------------
__global__ void combine_kernel(const float* __restrict__ x_res, const float* __restrict__ y,
                               const float* __restrict__ b2, const int* __restrict__ tok_e,
                               const float* __restrict__ tok_g, const int* __restrict__ tok_row,
                               float* __restrict__ out) {
    int t = blockIdx.x;
    int c = blockIdx.y * 256 + threadIdx.x;
    int e0 = tok_e[t*2], e1 = tok_e[t*2+1];
    float g0 = tok_g[t*2], g1 = tok_g[t*2+1];
    int r0 = tok_row[t*2], r1 = tok_row[t*2+1];
    float v = x_res[(size_t)t * DIMC + c]
            + g0 * (y[(size_t)r0 * DIMC + c] + b2[(size_t)e0 * DIMC + c])
            + g1 * (y[(size_t)r1 * DIMC + c] + b2[(size_t)e1 * DIMC + c]);
    out[(size_t)t * DIMC + c] = v;
}

extern "C" void kernel_launch(void* const* d_in, const int* in_sizes, int n_in,
                              void* d_out, int out_size, void* d_ws, size_t ws_size,
                              hipStream_t stream) {
    const float* x      = (const float*)d_in[0];
    const float* ln1_g  = (const float*)d_in[1];
    const float* ln1_b  = (const float*)d_in[2];
    const float* qkv_w  = (const float*)d_in[3];
    const float* qkv_b  = (const float*)d_in[4];
    const float* proj_w = (const float*)d_in[5];
    const float* proj_b = (const float*)d_in[6];
    const float* ln2_g  = (const float*)d_in[7];
    const float* ln2_b  = (const float*)d_in[8];
    const float* gate_w = (const float*)d_in[9];
    const float* w1     = (const float*)d_in[10];
    const float* b1     = (const float*)d_in[11];
    const float* w2     = (const float*)d_in[12];
    const float* b2     = (const float*)d_in[13];
    float* out = (float*)d_out;

    char* p = (char*)d_ws;
    auto alloc = [&](size_t nbytes) {
        void* r = (void*)p;
        p += (nbytes + 255) & ~(size_t)255;
        return r;
    };
    unsigned short* xn1_h   = (unsigned short*)alloc((size_t)TT * DIMC * 2);
    unsigned short* xn1_l   = (unsigned short*)alloc((size_t)TT * DIMC * 2);
    float*          qkv     = (float*)alloc((size_t)TT * 2304 * 4);
    unsigned short* ao_h    = (unsigned short*)alloc((size_t)TT * DIMC * 2);
    unsigned short* ao_l    = (unsigned short*)alloc((size_t)TT * DIMC * 2);
    float*          x_res   = (float*)alloc((size_t)TT * DIMC * 4);
    float*          xn2_f   = (float*)alloc((size_t)TT * DIMC * 4);
    unsigned short* xn2_bf  = (unsigned short*)alloc((size_t)TT * DIMC * 2);
    unsigned short* h       = (unsigned short*)alloc((size_t)CAP_ROWS * HID * 2);
    float*          y       = (float*)alloc((size_t)CAP_ROWS * DIMC * 4);
    unsigned short* w1t     = (unsigned short*)alloc((size_t)EXPERTS * DIMC * HID * 2);
    unsigned short* w2t     = (unsigned short*)alloc((size_t)EXPERTS * DIMC * HID * 2);
    unsigned short* qwt_h   = (unsigned short*)alloc((size_t)DIMC * 2304 * 2);
    unsigned short* qwt_l   = (unsigned short*)alloc((size_t)DIMC * 2304 * 2);
    unsigned short* pwt_h   = (unsigned short*)alloc((size_t)DIMC * DIMC * 2);
    unsigned short* pwt_l   = (unsigned short*)alloc((size_t)DIMC * DIMC * 2);
    float*          tok_g   = (float*)alloc((size_t)2 * TT * 4);
    int*            tok_e   = (int*)alloc((size_t)2 * TT * 4);
    int*            tok_row = (int*)alloc((size_t)2 * TT * 4);
    int*            row2tok = (int*)alloc((size_t)CAP_ROWS * 4);
    int*            counts  = (int*)alloc(32 * 4);
    int*            offsets = (int*)alloc(32 * 4);
    int*            cursor  = (int*)alloc(32 * 4);

    init_kernel<<<(CAP_ROWS + 255) / 256, 256, 0, stream>>>(counts, row2tok, CAP_ROWS);

    // weight transposes (independent of activations)
    transpose_bf16<<<dim3(HID / 64, DIMC / 64, EXPERTS), 256, 0, stream>>>(w1, w1t, DIMC, HID);
    transpose_bf16<<<dim3(DIMC / 64, HID / 64, EXPERTS), 256, 0, stream>>>(w2, w2t, HID, DIMC);
    transpose_split_bf16<<<dim3(2304 / 64, DIMC / 64), 256, 0, stream>>>(qkv_w, qwt_h, qwt_l,
                                                                         DIMC, 2304);
    transpose_split_bf16<<<dim3(DIMC / 64, DIMC / 64), 256, 0, stream>>>(proj_w, pwt_h, pwt_l,
                                                                         DIMC, DIMC);

    ln_kernel<<<TT, 256, 0, stream>>>(x, ln1_g, ln1_b, nullptr, xn1_h, xn1_l);

    mfma_gemm_split<0><<<dim3((TT + 63) / 64, 2304 / 64), 256, 0, stream>>>(
        xn1_h, xn1_l, qwt_h, qwt_l, qkv_b, nullptr, qkv, TT, 2304, DIMC);

    attn_mfma_kernel<<<dim3(BB * HEADS, 4), 256, 0, stream>>>(qkv, ao_h, ao_l);

    mfma_gemm_split<1><<<dim3((TT + 63) / 64, DIMC / 64), 256, 0, stream>>>(
        ao_h, ao_l, pwt_h, pwt_l, proj_b, x, x_res, TT, DIMC, DIMC);

    ln_kernel<<<TT, 256, 0, stream>>>(x_res, ln2_g, ln2_b, xn2_f, xn2_bf, nullptr);

    gate_kernel<<<TT, 64, 0, stream>>>(xn2_f, gate_w, tok_e, tok_g, counts);

    offsets_kernel<<<1, 64, 0, stream>>>(counts, offsets, cursor);

    fill_kernel<<<(TT + 255) / 256, 256, 0, stream>>>(tok_e, cursor, row2tok, tok_row);

    mfma_gemm_grouped<1, 1, 1><<<dim3(CAP_ROWS / 64, HID / 64), 256, 0, stream>>>(
        xn2_bf, w1t, b1, offsets, row2tok, h, HID, DIMC);

    mfma_gemm_grouped<0, 0, 0><<<dim3(CAP_ROWS / 64, DIMC / 64), 256, 0, stream>>>(
        h, w2t, nullptr, offsets, row2tok, y, DIMC, HID);

    combine_kernel<<<dim3(TT, 3), 256, 0, stream>>>(x_res, y, b2, tok_e, tok_g, tok_row, out);
}

// Round 8
// 328.461 us; speedup vs baseline: 2.6292x; 1.0278x over previous
//
#include <hip/hip_runtime.h>
#include <hip/hip_bf16.h>
#include <math.h>

#define DIMC 768
#define HEADS 12
#define HD 64
#define EXPERTS 8
#define HID 3072
#define BB 8
#define NN 196
#define TT (BB*NN)      // 1568
#define CAP_ROWS 4224   // 2*TT + 8*128 headroom, multiple of 128
#define LN_EPS 1e-5f

typedef float f32x4_t __attribute__((ext_vector_type(4)));
typedef short bf16x8_t __attribute__((ext_vector_type(8)));
typedef unsigned short u16x8_t __attribute__((ext_vector_type(8)));

__device__ __forceinline__ unsigned short f2bf(float f) {
    unsigned int u = __float_as_uint(f);
    u += 0x7FFFu + ((u >> 16) & 1u);   // round-to-nearest-even
    return (unsigned short)(u >> 16);
}
__device__ __forceinline__ float bf2f(unsigned short u) {
    return __uint_as_float(((unsigned int)u) << 16);
}

// ---------------- LayerNorm: one block per token, 256 threads, D=768 ----------------
__global__ void ln_kernel(const float* __restrict__ x, const float* __restrict__ g,
                          const float* __restrict__ b, float* __restrict__ out_f,
                          unsigned short* __restrict__ out_hi,
                          unsigned short* __restrict__ out_lo) {
    int t = blockIdx.x;
    const float* xr = x + (size_t)t * DIMC;
    int tid = threadIdx.x;
    float v0 = xr[tid], v1 = xr[tid + 256], v2 = xr[tid + 512];
    __shared__ float red[256];
    red[tid] = v0 + v1 + v2;
    __syncthreads();
    for (int off = 128; off > 0; off >>= 1) {
        if (tid < off) red[tid] += red[tid + off];
        __syncthreads();
    }
    float mu = red[0] * (1.0f / DIMC);
    __syncthreads();
    float d0 = v0 - mu, d1 = v1 - mu, d2 = v2 - mu;
    red[tid] = d0*d0 + d1*d1 + d2*d2;
    __syncthreads();
    for (int off = 128; off > 0; off >>= 1) {
        if (tid < off) red[tid] += red[tid + off];
        __syncthreads();
    }
    float rstd = rsqrtf(red[0] * (1.0f / DIMC) + LN_EPS);
    float o0 = d0 * rstd * g[tid]       + b[tid];
    float o1 = d1 * rstd * g[tid + 256] + b[tid + 256];
    float o2 = d2 * rstd * g[tid + 512] + b[tid + 512];
    if (out_f) {
        float* o = out_f + (size_t)t * DIMC;
        o[tid] = o0; o[tid + 256] = o1; o[tid + 512] = o2;
    }
    if (out_hi) {
        unsigned short* o = out_hi + (size_t)t * DIMC;
        unsigned short h0 = f2bf(o0), h1 = f2bf(o1), h2 = f2bf(o2);
        o[tid] = h0; o[tid + 256] = h1; o[tid + 512] = h2;
        if (out_lo) {
            unsigned short* ol = out_lo + (size_t)t * DIMC;
            ol[tid]       = f2bf(o0 - bf2f(h0));
            ol[tid + 256] = f2bf(o1 - bf2f(h1));
            ol[tid + 512] = f2bf(o2 - bf2f(h2));
        }
    }
}

// ---------------- MFMA attention, split-precision (validated round 7) ----------------
__global__ void attn_mfma_kernel(const float* __restrict__ qkv,
                                 unsigned short* __restrict__ ao_h,
                                 unsigned short* __restrict__ ao_l) {
    __shared__ float ps[64][224];
    __shared__ unsigned short QsH[64 * 64], QsL[64 * 64];
    __shared__ unsigned short KsH[64 * 64], KsL[64 * 64];

    int bh = blockIdx.x;
    int b = bh / HEADS, h = bh % HEADS;
    int q0 = blockIdx.y * 64;
    const float* base = qkv + (size_t)b * NN * 2304 + h * 64;

    int tid = threadIdx.x;
    int sr = tid >> 3, sq = tid & 7;
    int lane = tid & 63;
    int wid = tid >> 6;
    int wm = (wid >> 1) * 32;
    int wn = (wid & 1) * 32;
    int lrow = lane & 15;
    int lq = lane >> 4;
    int colb_base = lq * 16;

    #pragma unroll
    for (int p = 0; p < 2; ++p) {
        int r = sr + p * 32;
        int n = q0 + r;
        float v[8] = {0.f,0.f,0.f,0.f,0.f,0.f,0.f,0.f};
        if (n < NN) {
            float4 a0 = *(const float4*)(base + (size_t)n * 2304 + sq * 8);
            float4 a1 = *(const float4*)(base + (size_t)n * 2304 + sq * 8 + 4);
            v[0]=a0.x; v[1]=a0.y; v[2]=a0.z; v[3]=a0.w;
            v[4]=a1.x; v[5]=a1.y; v[6]=a1.z; v[7]=a1.w;
        }
        u16x8_t hv, lv;
        #pragma unroll
        for (int t = 0; t < 8; ++t) {
            unsigned short hh = f2bf(v[t]);
            hv[t] = hh; lv[t] = f2bf(v[t] - bf2f(hh));
        }
        int off = r * 128 + ((sq * 16) ^ ((r & 7) << 4));
        *(u16x8_t*)((char*)QsH + off) = hv;
        *(u16x8_t*)((char*)QsL + off) = lv;
    }

    for (int kt = 0; kt < 4; ++kt) {
        int j0 = kt * 64;
        __syncthreads();
        #pragma unroll
        for (int p = 0; p < 2; ++p) {
            int r = sr + p * 32;
            int n = j0 + r;
            float v[8] = {0.f,0.f,0.f,0.f,0.f,0.f,0.f,0.f};
            if (n < NN) {
                float4 a0 = *(const float4*)(base + (size_t)n * 2304 + 768 + sq * 8);
                float4 a1 = *(const float4*)(base + (size_t)n * 2304 + 768 + sq * 8 + 4);
                v[0]=a0.x; v[1]=a0.y; v[2]=a0.z; v[3]=a0.w;
                v[4]=a1.x; v[5]=a1.y; v[6]=a1.z; v[7]=a1.w;
            }
            u16x8_t hv, lv;
            #pragma unroll
            for (int t = 0; t < 8; ++t) {
                unsigned short hh = f2bf(v[t]);
                hv[t] = hh; lv[t] = f2bf(v[t] - bf2f(hh));
            }
            int off = r * 128 + ((sq * 16) ^ ((r & 7) << 4));
            *(u16x8_t*)((char*)KsH + off) = hv;
            *(u16x8_t*)((char*)KsL + off) = lv;
        }
        __syncthreads();

        f32x4_t acc[2][2] = {};
        #pragma unroll
        for (int kk = 0; kk < 2; ++kk) {
            int colb = kk * 64 + colb_base;
            bf16x8_t qh[2], ql[2], kh[2], kl[2];
            #pragma unroll
            for (int i = 0; i < 2; ++i) {
                int ra = wm + i * 16 + lrow;
                int oa = ra * 128 + (colb ^ ((ra & 7) << 4));
                qh[i] = *(const bf16x8_t*)((const char*)QsH + oa);
                ql[i] = *(const bf16x8_t*)((const char*)QsL + oa);
                int rb = wn + i * 16 + lrow;
                int ob = rb * 128 + (colb ^ ((rb & 7) << 4));
                kh[i] = *(const bf16x8_t*)((const char*)KsH + ob);
                kl[i] = *(const bf16x8_t*)((const char*)KsL + ob);
            }
            #pragma unroll
            for (int mi = 0; mi < 2; ++mi)
                #pragma unroll
                for (int ni = 0; ni < 2; ++ni) {
                    acc[mi][ni] = __builtin_amdgcn_mfma_f32_16x16x32_bf16(
                        qh[mi], kh[ni], acc[mi][ni], 0, 0, 0);
                    acc[mi][ni] = __builtin_amdgcn_mfma_f32_16x16x32_bf16(
                        qh[mi], kl[ni], acc[mi][ni], 0, 0, 0);
                    acc[mi][ni] = __builtin_amdgcn_mfma_f32_16x16x32_bf16(
                        ql[mi], kh[ni], acc[mi][ni], 0, 0, 0);
                }
        }
        #pragma unroll
        for (int mi = 0; mi < 2; ++mi)
            #pragma unroll
            for (int ni = 0; ni < 2; ++ni) {
                int jc = j0 + wn + ni * 16 + lrow;
                if (jc < 224) {
                    int rowb = wm + mi * 16 + lq * 4;
                    #pragma unroll
                    for (int j = 0; j < 4; ++j)
                        ps[rowb + j][jc] = acc[mi][ni][j] * 0.125f;
                }
            }
    }
    __syncthreads();

    {
        int i = tid >> 2, l = tid & 3;
        float mx = -1e30f;
        for (int j = l; j < NN; j += 4) mx = fmaxf(mx, ps[i][j]);
        mx = fmaxf(mx, __shfl_xor(mx, 1, 4));
        mx = fmaxf(mx, __shfl_xor(mx, 2, 4));
        float sum = 0.f;
        for (int j = l; j < NN; j += 4) { float e = expf(ps[i][j] - mx); ps[i][j] = e; sum += e; }
        sum += __shfl_xor(sum, 1, 4);
        sum += __shfl_xor(sum, 2, 4);
        float inv = 1.f / sum;
        for (int j = l; j < NN; j += 4) ps[i][j] *= inv;
    }

    f32x4_t oacc[2][2] = {};
    for (int kt = 0; kt < 4; ++kt) {
        int j0 = kt * 64;
        __syncthreads();
        #pragma unroll
        for (int p = 0; p < 2; ++p) {
            int r = sr + p * 32;
            int n = j0 + r;
            float v[8] = {0.f,0.f,0.f,0.f,0.f,0.f,0.f,0.f};
            if (n < NN) {
                float4 a0 = *(const float4*)(base + (size_t)n * 2304 + 1536 + sq * 8);
                float4 a1 = *(const float4*)(base + (size_t)n * 2304 + 1536 + sq * 8 + 4);
                v[0]=a0.x; v[1]=a0.y; v[2]=a0.z; v[3]=a0.w;
                v[4]=a1.x; v[5]=a1.y; v[6]=a1.z; v[7]=a1.w;
            }
            #pragma unroll
            for (int t = 0; t < 8; ++t) {
                int d = sq * 8 + t;
                unsigned short hh = f2bf(v[t]);
                int off = d * 128 + ((r * 2) ^ ((d & 7) << 4));
                *(unsigned short*)((char*)KsH + off) = hh;
                *(unsigned short*)((char*)KsL + off) = f2bf(v[t] - bf2f(hh));
            }
        }
        __syncthreads();

        int kkmax = (kt == 3) ? 1 : 2;
        for (int kk = 0; kk < kkmax; ++kk) {
            int colb = kk * 64 + colb_base;
            bf16x8_t pah[2], pal[2], vh[2], vl[2];
            #pragma unroll
            for (int i = 0; i < 2; ++i) {
                int ra = wm + i * 16 + lrow;
                const float* prow = &ps[ra][j0 + kk * 32 + lq * 8];
                float4 a0 = *(const float4*)prow;
                float4 a1 = *(const float4*)(prow + 4);
                float vv[8] = {a0.x,a0.y,a0.z,a0.w,a1.x,a1.y,a1.z,a1.w};
                u16x8_t hv, lv;
                #pragma unroll
                for (int t = 0; t < 8; ++t) {
                    unsigned short hh = f2bf(vv[t]);
                    hv[t] = hh; lv[t] = f2bf(vv[t] - bf2f(hh));
                }
                pah[i] = *(bf16x8_t*)&hv;
                pal[i] = *(bf16x8_t*)&lv;
                int rb = wn + i * 16 + lrow;
                int ob = rb * 128 + (colb ^ ((rb & 7) << 4));
                vh[i] = *(const bf16x8_t*)((const char*)KsH + ob);
                vl[i] = *(const bf16x8_t*)((const char*)KsL + ob);
            }
            #pragma unroll
            for (int mi = 0; mi < 2; ++mi)
                #pragma unroll
                for (int ni = 0; ni < 2; ++ni) {
                    oacc[mi][ni] = __builtin_amdgcn_mfma_f32_16x16x32_bf16(
                        pah[mi], vh[ni], oacc[mi][ni], 0, 0, 0);
                    oacc[mi][ni] = __builtin_amdgcn_mfma_f32_16x16x32_bf16(
                        pah[mi], vl[ni], oacc[mi][ni], 0, 0, 0);
                    oacc[mi][ni] = __builtin_amdgcn_mfma_f32_16x16x32_bf16(
                        pal[mi], vh[ni], oacc[mi][ni], 0, 0, 0);
                }
        }
    }

    #pragma unroll
    for (int mi = 0; mi < 2; ++mi)
        #pragma unroll
        for (int ni = 0; ni < 2; ++ni) {
            int col = h * 64 + wn + ni * 16 + lrow;
            #pragma unroll
            for (int j = 0; j < 4; ++j) {
                int n = q0 + wm + mi * 16 + lq * 4 + j;
                if (n < NN) {
                    float v = oacc[mi][ni][j];
                    unsigned short hh = f2bf(v);
                    size_t o = (size_t)(b * NN + n) * DIMC + col;
                    ao_h[o] = hh;
                    ao_l[o] = f2bf(v - bf2f(hh));
                }
            }
        }
}

// ---------------- gate: one wave per token (fp32 — expert choice must match ref) ----------------
__global__ void gate_kernel(const float* __restrict__ xn, const float* __restrict__ gw,
                            int* __restrict__ tok_e, float* __restrict__ tok_g,
                            int* __restrict__ counts) {
    int t = blockIdx.x;
    int lane = threadIdx.x;  // 64
    float acc[8] = {};
    const float* xr = xn + (size_t)t * DIMC;
    for (int i = lane; i < DIMC; i += 64) {
        float xi = xr[i];
        const float* gr = gw + (size_t)i * 8;
        #pragma unroll
        for (int e = 0; e < 8; ++e) acc[e] += xi * gr[e];
    }
    #pragma unroll
    for (int e = 0; e < 8; ++e) {
        #pragma unroll
        for (int off = 32; off > 0; off >>= 1) acc[e] += __shfl_down(acc[e], off, 64);
    }
    if (lane == 0) {
        int e0 = 0; float l0 = acc[0];
        #pragma unroll
        for (int e = 1; e < 8; ++e) if (acc[e] > l0) { l0 = acc[e]; e0 = e; }
        int e1 = -1; float l1 = -3e38f;
        #pragma unroll
        for (int e = 0; e < 8; ++e) if (e != e0 && acc[e] > l1) { l1 = acc[e]; e1 = e; }
        float pp = expf(l1 - l0);
        float g0 = 1.f / (1.f + pp);
        float g1 = pp / (1.f + pp);
        tok_e[t*2] = e0; tok_e[t*2+1] = e1;
        tok_g[t*2] = g0; tok_g[t*2+1] = g1;
        atomicAdd(&counts[e0], 1);
        atomicAdd(&counts[e1], 1);
    }
}

__global__ void init_kernel(int* __restrict__ counts, int* __restrict__ row2tok, int cap) {
    int i = blockIdx.x * blockDim.x + threadIdx.x;
    if (i < 8) counts[i] = 0;
    if (i < cap) row2tok[i] = -1;
}

__global__ void offsets_kernel(const int* __restrict__ counts, int* __restrict__ offsets,
                               int* __restrict__ cursor) {
    if (threadIdx.x == 0 && blockIdx.x == 0) {
        int off = 0;
        for (int e = 0; e < 8; ++e) {
            offsets[e] = off;
            cursor[e]  = off;
            off += ((counts[e] + 127) / 128) * 128;  // pad each segment to BM=128
        }
        offsets[8] = off;
    }
}

__global__ void fill_kernel(const int* __restrict__ tok_e, int* __restrict__ cursor,
                            int* __restrict__ row2tok, int* __restrict__ tok_row) {
    int t = blockIdx.x * blockDim.x + threadIdx.x;
    if (t >= TT) return;
    #pragma unroll
    for (int k = 0; k < 2; ++k) {
        int e = tok_e[t*2+k];
        int slot = atomicAdd(&cursor[e], 1);
        row2tok[slot] = t;
        tok_row[t*2+k] = slot;
    }
}

// ---------------- batched transpose + fp32->bf16: src [B][R][C] -> dst [B][C][R] ----------------
__global__ void transpose_bf16(const float* __restrict__ src, unsigned short* __restrict__ dst,
                               int R, int C) {
    __shared__ float tile[64][65];
    const float* s = src + (size_t)blockIdx.z * R * C;
    unsigned short* d = dst + (size_t)blockIdx.z * R * C;
    int c0 = blockIdx.x * 64, r0 = blockIdx.y * 64;
    int tid = threadIdx.x;
    int tr = tid >> 4;            // 0..15
    int tc = (tid & 15) * 4;      // 0..60
    #pragma unroll
    for (int p = 0; p < 4; ++p) {
        int r = tr + p * 16;
        const float4 v = *(const float4*)(s + (size_t)(r0 + r) * C + c0 + tc);
        tile[r][tc+0] = v.x; tile[r][tc+1] = v.y; tile[r][tc+2] = v.z; tile[r][tc+3] = v.w;
    }
    __syncthreads();
    #pragma unroll
    for (int p = 0; p < 4; ++p) {
        int c = tr + p * 16;      // local col -> dst row
        ushort4 o;
        o.x = f2bf(tile[tc+0][c]);
        o.y = f2bf(tile[tc+1][c]);
        o.z = f2bf(tile[tc+2][c]);
        o.w = f2bf(tile[tc+3][c]);
        *(ushort4*)(d + (size_t)(c0 + c) * R + r0 + tc) = o;
    }
}

// ---------------- transpose + hi/lo split: src [R][C] fp32 -> dh/dl [C][R] bf16 ----------------
__global__ void transpose_split_bf16(const float* __restrict__ src,
                                     unsigned short* __restrict__ dh,
                                     unsigned short* __restrict__ dl, int R, int C) {
    __shared__ float tile[64][65];
    int c0 = blockIdx.x * 64, r0 = blockIdx.y * 64;
    int tid = threadIdx.x;
    int tr = tid >> 4;
    int tc = (tid & 15) * 4;
    #pragma unroll
    for (int p = 0; p < 4; ++p) {
        int r = tr + p * 16;
        const float4 v = *(const float4*)(src + (size_t)(r0 + r) * C + c0 + tc);
        tile[r][tc+0] = v.x; tile[r][tc+1] = v.y; tile[r][tc+2] = v.z; tile[r][tc+3] = v.w;
    }
    __syncthreads();
    #pragma unroll
    for (int p = 0; p < 4; ++p) {
        int c = tr + p * 16;
        ushort4 h, l;
        float v0 = tile[tc+0][c], v1 = tile[tc+1][c], v2 = tile[tc+2][c], v3 = tile[tc+3][c];
        h.x = f2bf(v0); l.x = f2bf(v0 - bf2f(h.x));
        h.y = f2bf(v1); l.y = f2bf(v1 - bf2f(h.y));
        h.z = f2bf(v2); l.z = f2bf(v2 - bf2f(h.z));
        h.w = f2bf(v3); l.w = f2bf(v3 - bf2f(h.w));
        size_t off = (size_t)(c0 + c) * R + r0 + tc;
        *(ushort4*)(dh + off) = h;
        *(ushort4*)(dl + off) = l;
    }
}

// ---------------- split-precision MFMA GEMM (validated round 6) ----------------
template<int RES>
__global__ void mfma_gemm_split(const unsigned short* __restrict__ Ah,
                                const unsigned short* __restrict__ Al,
                                const unsigned short* __restrict__ Bth,
                                const unsigned short* __restrict__ Btl,
                                const float* __restrict__ bias,
                                const float* __restrict__ res,
                                float* __restrict__ C,
                                int M, int N, int K) {
    __shared__ unsigned short AsH[64 * 64];
    __shared__ unsigned short AsL[64 * 64];
    __shared__ unsigned short BsH[64 * 64];
    __shared__ unsigned short BsL[64 * 64];

    int m0 = blockIdx.x * 64;
    int n0 = blockIdx.y * 64;
    int tid = threadIdx.x;
    int sr = tid >> 3;
    int sq = tid & 7;
    int lane = tid & 63;
    int wid = tid >> 6;
    int wm = (wid >> 1) * 32;
    int wn = (wid & 1) * 32;
    int colb_base = (lane >> 4) * 16;
    int lrow = lane & 15;

    f32x4_t acc[2][2] = {};

    for (int k0 = 0; k0 < K; k0 += 64) {
        #pragma unroll
        for (int p = 0; p < 2; ++p) {
            int r = sr + p * 32;
            int swz = (sq * 16) ^ ((r & 7) << 4);
            int4 vah = {0,0,0,0}, val = {0,0,0,0};
            if (m0 + r < M) {
                size_t aoff = (size_t)(m0 + r) * K + k0 + sq * 8;
                vah = *(const int4*)(Ah + aoff);
                val = *(const int4*)(Al + aoff);
            }
            *(int4*)((char*)AsH + r * 128 + swz) = vah;
            *(int4*)((char*)AsL + r * 128 + swz) = val;
            size_t boff = (size_t)(n0 + r) * K + k0 + sq * 8;
            *(int4*)((char*)BsH + r * 128 + swz) = *(const int4*)(Bth + boff);
            *(int4*)((char*)BsL + r * 128 + swz) = *(const int4*)(Btl + boff);
        }
        __syncthreads();
        #pragma unroll
        for (int kk = 0; kk < 2; ++kk) {
            int colb = kk * 64 + colb_base;
            bf16x8_t ah[2], al[2], bh[2], bl[2];
            #pragma unroll
            for (int i = 0; i < 2; ++i) {
                int ra = wm + i * 16 + lrow;
                int oa = ra * 128 + (colb ^ ((ra & 7) << 4));
                ah[i] = *(const bf16x8_t*)((const char*)AsH + oa);
                al[i] = *(const bf16x8_t*)((const char*)AsL + oa);
                int rb = wn + i * 16 + lrow;
                int ob = rb * 128 + (colb ^ ((rb & 7) << 4));
                bh[i] = *(const bf16x8_t*)((const char*)BsH + ob);
                bl[i] = *(const bf16x8_t*)((const char*)BsL + ob);
            }
            #pragma unroll
            for (int mi = 0; mi < 2; ++mi)
                #pragma unroll
                for (int ni = 0; ni < 2; ++ni) {
                    acc[mi][ni] = __builtin_amdgcn_mfma_f32_16x16x32_bf16(
                        ah[mi], bh[ni], acc[mi][ni], 0, 0, 0);
                    acc[mi][ni] = __builtin_amdgcn_mfma_f32_16x16x32_bf16(
                        ah[mi], bl[ni], acc[mi][ni], 0, 0, 0);
                    acc[mi][ni] = __builtin_amdgcn_mfma_f32_16x16x32_bf16(
                        al[mi], bh[ni], acc[mi][ni], 0, 0, 0);
                }
        }
        __syncthreads();
    }

    #pragma unroll
    for (int mi = 0; mi < 2; ++mi) {
        #pragma unroll
        for (int ni = 0; ni < 2; ++ni) {
            int col = n0 + wn + ni * 16 + lrow;
            #pragma unroll
            for (int j = 0; j < 4; ++j) {
                int row = m0 + wm + mi * 16 + (lane >> 4) * 4 + j;
                if (row < M) {
                    float v = acc[mi][ni][j] + bias[col];
                    if (RES) v += res[(size_t)row * N + col];
                    C[(size_t)row * N + col] = v;
                }
            }
        }
    }
}

// ---------------- grouped bf16 MFMA GEMM, 128x128 tile + XCD-chunked swizzle ----------------
// 1D grid nwg = nxb * (N/64... N/128). Logical y-major: L = ypanel*nxb + xb.
// 4 waves (2x2), each wave 64x64 out = 4x4 16x16 frags. BK=64.
template<int GATHER, int GELU, int OUT_BF16>
__global__ void mfma_gemm_grouped128(const unsigned short* __restrict__ A,
                                     const unsigned short* __restrict__ Bt,
                                     const float* __restrict__ bias,
                                     const int* __restrict__ offsets,
                                     const int* __restrict__ row2tok,
                                     void* __restrict__ Cout,
                                     int N, int K, int nxb) {
    __shared__ unsigned short As[128 * 64];   // 16 KB
    __shared__ unsigned short Bs[128 * 64];   // 16 KB
    __shared__ int toks[128];

    // bijective XCD-chunked remap (m204): each XCD gets a contiguous logical range
    int nwg = gridDim.x;
    int p = blockIdx.x;
    int q = nwg >> 3, r8 = nwg & 7;
    int xcd = p & 7, slot = p >> 3;
    int L = (xcd < r8) ? xcd * (q + 1) + slot
                       : r8 * (q + 1) + (xcd - r8) * q + slot;
    int xb = L % nxb;
    int n0 = (L / nxb) * 128;
    int r0 = xb * 128;
    if (r0 >= offsets[8]) return;
    int e = 0;
    while (r0 >= offsets[e + 1]) ++e;

    int tid = threadIdx.x;
    if (GATHER) {
        if (tid < 128) toks[tid] = row2tok[r0 + tid];
        __syncthreads();
    }
    const unsigned short* Be = Bt + (size_t)e * N * K;

    int sr = tid >> 3, sq = tid & 7;
    int lane = tid & 63, wid = tid >> 6;
    int wm = (wid >> 1) * 64;
    int wn = (wid & 1) * 64;
    int lrow = lane & 15, lq = lane >> 4;
    int colb_base = lq * 16;

    f32x4_t acc[4][4] = {};

    for (int k0 = 0; k0 < K; k0 += 64) {
        #pragma unroll
        for (int pp = 0; pp < 4; ++pp) {
            int rr = sr + pp * 32;
            int swz = (sq * 16) ^ ((rr & 7) << 4);
            int4 va = {0, 0, 0, 0};
            if (GATHER) {
                int tok = toks[rr];
                if (tok >= 0) va = *(const int4*)(A + (size_t)tok * K + k0 + sq * 8);
            } else {
                va = *(const int4*)(A + (size_t)(r0 + rr) * K + k0 + sq * 8);
            }
            *(int4*)((char*)As + rr * 128 + swz) = va;
            int4 vb = *(const int4*)(Be + (size_t)(n0 + rr) * K + k0 + sq * 8);
            *(int4*)((char*)Bs + rr * 128 + swz) = vb;
        }
        __syncthreads();
        #pragma unroll
        for (int kk = 0; kk < 2; ++kk) {
            int colb = kk * 64 + colb_base;
            bf16x8_t a[4], b[4];
            #pragma unroll
            for (int i = 0; i < 4; ++i) {
                int ra = wm + i * 16 + lrow;
                a[i] = *(const bf16x8_t*)((const char*)As + ra * 128 + (colb ^ ((ra & 7) << 4)));
                int rb = wn + i * 16 + lrow;
                b[i] = *(const bf16x8_t*)((const char*)Bs + rb * 128 + (colb ^ ((rb & 7) << 4)));
            }
            #pragma unroll
            for (int mi = 0; mi < 4; ++mi)
                #pragma unroll
                for (int ni = 0; ni < 4; ++ni)
                    acc[mi][ni] = __builtin_amdgcn_mfma_f32_16x16x32_bf16(
                        a[mi], b[ni], acc[mi][ni], 0, 0, 0);
        }
        __syncthreads();
    }

    #pragma unroll
    for (int mi = 0; mi < 4; ++mi) {
        #pragma unroll
        for (int ni = 0; ni < 4; ++ni) {
            int col = n0 + wn + ni * 16 + lrow;
            float bv = GELU ? bias[(size_t)e * N + col] : 0.f;
            #pragma unroll
            for (int j = 0; j < 4; ++j) {
                int row = r0 + wm + mi * 16 + lq * 4 + j;
                float v = acc[mi][ni][j] + bv;
                if (GELU) v = 0.5f * v * (1.f + erff(v * 0.70710678f));
                if (OUT_BF16)
                    ((unsigned short*)Cout)[(size_t)row * N + col] = f2bf(v);
                else
                    ((float*)Cout)[(size_t)row * N + col] = v;
            }
        }
    }
}

// ---------------- combine: out = x_res + sum_k g_k*(y[row_k] + b2[e_k]) ----------------
__global__ void combine_kernel(const float* __restrict__ x_res, const float* __restrict__ y,
                               const float* __restrict__ b2, const int* __restrict__ tok_e,
                               const float* __restrict__ tok_g, const int* __restrict__ tok_row,
                               float* __restrict__ out) {
    int t = blockIdx.x;
    int c = blockIdx.y * 256 + threadIdx.x;
    int e0 = tok_e[t*2], e1 = tok_e[t*2+1];
    float g0 = tok_g[t*2], g1 = tok_g[t*2+1];
    int r0 = tok_row[t*2], r1 = tok_row[t*2+1];
    float v = x_res[(size_t)t * DIMC + c]
            + g0 * (y[(size_t)r0 * DIMC + c] + b2[(size_t)e0 * DIMC + c])
            + g1 * (y[(size_t)r1 * DIMC + c] + b2[(size_t)e1 * DIMC + c]);
    out[(size_t)t * DIMC + c] = v;
}

extern "C" void kernel_launch(void* const* d_in, const int* in_sizes, int n_in,
                              void* d_out, int out_size, void* d_ws, size_t ws_size,
                              hipStream_t stream) {
    const float* x      = (const float*)d_in[0];
    const float* ln1_g  = (const float*)d_in[1];
    const float* ln1_b  = (const float*)d_in[2];
    const float* qkv_w  = (const float*)d_in[3];
    const float* qkv_b  = (const float*)d_in[4];
    const float* proj_w = (const float*)d_in[5];
    const float* proj_b = (const float*)d_in[6];
    const float* ln2_g  = (const float*)d_in[7];
    const float* ln2_b  = (const float*)d_in[8];
    const float* gate_w = (const float*)d_in[9];
    const float* w1     = (const float*)d_in[10];
    const float* b1     = (const float*)d_in[11];
    const float* w2     = (const float*)d_in[12];
    const float* b2     = (const float*)d_in[13];
    float* out = (float*)d_out;

    char* p = (char*)d_ws;
    auto alloc = [&](size_t nbytes) {
        void* r = (void*)p;
        p += (nbytes + 255) & ~(size_t)255;
        return r;
    };
    unsigned short* xn1_h   = (unsigned short*)alloc((size_t)TT * DIMC * 2);
    unsigned short* xn1_l   = (unsigned short*)alloc((size_t)TT * DIMC * 2);
    float*          qkv     = (float*)alloc((size_t)TT * 2304 * 4);
    unsigned short* ao_h    = (unsigned short*)alloc((size_t)TT * DIMC * 2);
    unsigned short* ao_l    = (unsigned short*)alloc((size_t)TT * DIMC * 2);
    float*          x_res   = (float*)alloc((size_t)TT * DIMC * 4);
    float*          xn2_f   = (float*)alloc((size_t)TT * DIMC * 4);
    unsigned short* xn2_bf  = (unsigned short*)alloc((size_t)TT * DIMC * 2);
    unsigned short* h       = (unsigned short*)alloc((size_t)CAP_ROWS * HID * 2);
    float*          y       = (float*)alloc((size_t)CAP_ROWS * DIMC * 4);
    unsigned short* w1t     = (unsigned short*)alloc((size_t)EXPERTS * DIMC * HID * 2);
    unsigned short* w2t     = (unsigned short*)alloc((size_t)EXPERTS * DIMC * HID * 2);
    unsigned short* qwt_h   = (unsigned short*)alloc((size_t)DIMC * 2304 * 2);
    unsigned short* qwt_l   = (unsigned short*)alloc((size_t)DIMC * 2304 * 2);
    unsigned short* pwt_h   = (unsigned short*)alloc((size_t)DIMC * DIMC * 2);
    unsigned short* pwt_l   = (unsigned short*)alloc((size_t)DIMC * DIMC * 2);
    float*          tok_g   = (float*)alloc((size_t)2 * TT * 4);
    int*            tok_e   = (int*)alloc((size_t)2 * TT * 4);
    int*            tok_row = (int*)alloc((size_t)2 * TT * 4);
    int*            row2tok = (int*)alloc((size_t)CAP_ROWS * 4);
    int*            counts  = (int*)alloc(32 * 4);
    int*            offsets = (int*)alloc(32 * 4);
    int*            cursor  = (int*)alloc(32 * 4);

    init_kernel<<<(CAP_ROWS + 255) / 256, 256, 0, stream>>>(counts, row2tok, CAP_ROWS);

    // weight transposes (independent of activations)
    transpose_bf16<<<dim3(HID / 64, DIMC / 64, EXPERTS), 256, 0, stream>>>(w1, w1t, DIMC, HID);
    transpose_bf16<<<dim3(DIMC / 64, HID / 64, EXPERTS), 256, 0, stream>>>(w2, w2t, HID, DIMC);
    transpose_split_bf16<<<dim3(2304 / 64, DIMC / 64), 256, 0, stream>>>(qkv_w, qwt_h, qwt_l,
                                                                         DIMC, 2304);
    transpose_split_bf16<<<dim3(DIMC / 64, DIMC / 64), 256, 0, stream>>>(proj_w, pwt_h, pwt_l,
                                                                         DIMC, DIMC);

    ln_kernel<<<TT, 256, 0, stream>>>(x, ln1_g, ln1_b, nullptr, xn1_h, xn1_l);

    mfma_gemm_split<0><<<dim3((TT + 63) / 64, 2304 / 64), 256, 0, stream>>>(
        xn1_h, xn1_l, qwt_h, qwt_l, qkv_b, nullptr, qkv, TT, 2304, DIMC);

    attn_mfma_kernel<<<dim3(BB * HEADS, 4), 256, 0, stream>>>(qkv, ao_h, ao_l);

    mfma_gemm_split<1><<<dim3((TT + 63) / 64, DIMC / 64), 256, 0, stream>>>(
        ao_h, ao_l, pwt_h, pwt_l, proj_b, x, x_res, TT, DIMC, DIMC);

    ln_kernel<<<TT, 256, 0, stream>>>(x_res, ln2_g, ln2_b, xn2_f, xn2_bf, nullptr);

    gate_kernel<<<TT, 64, 0, stream>>>(xn2_f, gate_w, tok_e, tok_g, counts);

    offsets_kernel<<<1, 64, 0, stream>>>(counts, offsets, cursor);

    fill_kernel<<<(TT + 255) / 256, 256, 0, stream>>>(tok_e, cursor, row2tok, tok_row);

    {
        int nxb = CAP_ROWS / 128;                       // 33
        int nwg1 = nxb * (HID / 128);                   // 33*24 = 792
        mfma_gemm_grouped128<1, 1, 1><<<nwg1, 256, 0, stream>>>(
            xn2_bf, w1t, b1, offsets, row2tok, h, HID, DIMC, nxb);

        int nwg2 = nxb * (DIMC / 128);                  // 33*6 = 198
        mfma_gemm_grouped128<0, 0, 0><<<nwg2, 256, 0, stream>>>(
            h, w2t, nullptr, offsets, row2tok, y, DIMC, HID, nxb);
    }

    combine_kernel<<<dim3(TT, 3), 256, 0, stream>>>(x_res, y, b2, tok_e, tok_g, tok_row, out);
}